// Round 1
// 1049.845 us; speedup vs baseline: 1.1805x; 1.1805x over previous
//
#include <hip/hip_runtime.h>
#include <hip/hip_bf16.h>
#include <math.h>

// ---------- problem constants ----------
// x (2,3,512,512); grid 64x64 tokens of 768 ch; 8 windows of 32x32=1024 tokens
// heads=8, HD=96, F=16, rope feat dim 64, ||feat||^2 = 32 exactly.

typedef __attribute__((ext_vector_type(8))) short short8;   // 8 bf16 (4 VGPRs)
typedef __attribute__((ext_vector_type(4))) float f32x4;    // MFMA accumulator
typedef __attribute__((ext_vector_type(4))) unsigned short us4;

// bf16 split helpers: v ~= hi + lo with ~16-bit effective mantissa
__device__ __forceinline__ unsigned short f2bf(float f) {
    unsigned u = __float_as_uint(f);
    return (unsigned short)((u + 0x7FFFu + ((u >> 16) & 1u)) >> 16);   // RNE
}
__device__ __forceinline__ float bf2f(unsigned short h) { return __uint_as_float(((unsigned)h) << 16); }
__device__ __forceinline__ void split4(float4 v, us4& h4, us4& l4) {
    unsigned short h0 = f2bf(v.x), h1 = f2bf(v.y), h2 = f2bf(v.z), h3 = f2bf(v.w);
    h4 = (us4){h0, h1, h2, h3};
    l4 = (us4){f2bf(v.x - bf2f(h0)), f2bf(v.y - bf2f(h1)),
               f2bf(v.z - bf2f(h2)), f2bf(v.w - bf2f(h3))};
}

// ---------------- bilinear 2x resize (clamp-to-edge == jax renormalized) ----------------
__global__ __launch_bounds__(256) void k_resize(const float* __restrict__ x, float* __restrict__ rx)
{
    int idx = blockIdx.x * 256 + threadIdx.x;           // < 6291456 exactly
    int X = idx & 1023;
    int Y = (idx >> 10) & 1023;
    int bc = idx >> 20;                                 // 0..5 (b*3+c)
    float sy = Y * 0.5f - 0.25f;
    float sx = X * 0.5f - 0.25f;
    int y0 = (int)floorf(sy), x0 = (int)floorf(sx);
    float fy = sy - (float)y0, fx = sx - (float)x0;
    int y1 = y0 + 1, x1 = x0 + 1;
    y0 = max(0, min(511, y0)); y1 = max(0, min(511, y1));
    x0 = max(0, min(511, x0)); x1 = max(0, min(511, x1));
    const float* p = x + (size_t)bc * (512 * 512);
    float v00 = p[y0 * 512 + x0], v01 = p[y0 * 512 + x1];
    float v10 = p[y1 * 512 + x0], v11 = p[y1 * 512 + x1];
    rx[idx] = (1.f - fy) * ((1.f - fx) * v00 + fx * v01) + fy * ((1.f - fx) * v10 + fx * v11);
}

// ---------------- rope relative table R[dy+31][dx+31] ----------------
__global__ void k_rsmall(float* __restrict__ rs)
{
    int e = blockIdx.x * 256 + threadIdx.x;
    if (e >= 63 * 63) return;
    float dy = (float)(e / 63 - 31);
    float dx = (float)(e % 63 - 31);
    float s = 0.f;
    for (int f = 0; f < 16; f++) {
        float invf = powf(10.0f, -(float)f / 16.0f);
        s += cosf(dx * invf) + cosf(dy * invf);
    }
    rs[e] = s;
}

// ---------------- resize conv as tile GEMM: tokens(8192) x K(256) x ch(768, 3 groups) ----------------
__global__ __launch_bounds__(256) void k_convr(
    const float* __restrict__ rx, const float* __restrict__ wgt,
    const float* __restrict__ bias, const float* __restrict__ pe,
    float* __restrict__ out)
{
    __shared__ float As[16][68];
    __shared__ float Bs[16][68];
    int tid = threadIdx.x;
    int m0 = blockIdx.y * 64;         // token tile
    int cbase = blockIdx.x * 64;      // channel tile (stays within one group: 256%64==0)
    int ic = cbase >> 8;              // input channel for this group
    int ar = tid >> 2, ac = (tid & 3) * 4;
    int ty = tid >> 4, tx = tid & 15;

    int mtok = m0 + ar;
    int w = mtok >> 10, l = mtok & 1023;
    int b = w >> 2, wm = (w >> 1) & 1, wn = w & 1;
    int gy = wm * 32 + (l >> 5), gx = wn * 32 + (l & 31);
    const float* abase = rx + ((size_t)(b * 3 + ic) * 1024 + gy * 16) * 1024 + gx * 16;
    const float* bbase = wgt + (size_t)(cbase + ar) * 256;

    float acc[4][4] = {};
    for (int k0 = 0; k0 < 256; k0 += 16) {
        float4 av = *(const float4*)(abase + (size_t)(k0 >> 4) * 1024 + ac);
        float4 bv = *(const float4*)(bbase + k0 + ac);
        As[ac + 0][ar] = av.x; As[ac + 1][ar] = av.y; As[ac + 2][ar] = av.z; As[ac + 3][ar] = av.w;
        Bs[ac + 0][ar] = bv.x; Bs[ac + 1][ar] = bv.y; Bs[ac + 2][ar] = bv.z; Bs[ac + 3][ar] = bv.w;
        __syncthreads();
#pragma unroll
        for (int k = 0; k < 16; k++) {
            float4 a4 = *(const float4*)&As[k][ty * 4];
            float4 b4 = *(const float4*)&Bs[k][tx * 4];
            float a[4] = {a4.x, a4.y, a4.z, a4.w};
            float bb2[4] = {b4.x, b4.y, b4.z, b4.w};
#pragma unroll
            for (int r = 0; r < 4; r++)
#pragma unroll
                for (int c = 0; c < 4; c++) acc[r][c] += a[r] * bb2[c];
        }
        __syncthreads();
    }
#pragma unroll
    for (int r = 0; r < 4; r++) {
        int t = m0 + ty * 4 + r;
        int tw = t >> 10, tl = t & 1023;
        int tgy = ((tw >> 1) & 1) * 32 + (tl >> 5);
        int tgx = (tw & 1) * 32 + (tl & 31);
#pragma unroll
        for (int c = 0; c < 4; c++) {
            int cc = cbase + tx * 4 + c;
            out[(size_t)t * 768 + cc] = acc[r][c] + bias[cc] + pe[(size_t)cc * 4096 + tgy * 64 + tgx];
        }
    }
}

// ---------------- origin conv as tile GEMM: tokens(8192) x K(64) x ch(768, 3 groups) ----------------
__global__ __launch_bounds__(256) void k_convo(
    const float* __restrict__ x, const float* __restrict__ wgt,
    const float* __restrict__ bias, float* __restrict__ out)
{
    __shared__ float As[16][68];
    __shared__ float Bs[16][68];
    int tid = threadIdx.x;
    int m0 = blockIdx.y * 64;
    int cbase = blockIdx.x * 64;
    int ic = cbase >> 8;
    int ar = tid >> 2, ac = (tid & 3) * 4;
    int ty = tid >> 4, tx = tid & 15;

    int mtok = m0 + ar;
    int w = mtok >> 10, l = mtok & 1023;
    int b = w >> 2, wm = (w >> 1) & 1, wn = w & 1;
    int gy = wm * 32 + (l >> 5), gx = wn * 32 + (l & 31);
    const float* abase = x + ((size_t)(b * 3 + ic) * 512 + gy * 8) * 512 + gx * 8;
    const float* bbase = wgt + (size_t)(cbase + ar) * 64;

    float acc[4][4] = {};
    for (int k0 = 0; k0 < 64; k0 += 16) {
        int k = k0 + ac;
        float4 av = *(const float4*)(abase + (size_t)(k >> 3) * 512 + (k & 7));
        float4 bv = *(const float4*)(bbase + k);
        As[ac + 0][ar] = av.x; As[ac + 1][ar] = av.y; As[ac + 2][ar] = av.z; As[ac + 3][ar] = av.w;
        Bs[ac + 0][ar] = bv.x; Bs[ac + 1][ar] = bv.y; Bs[ac + 2][ar] = bv.z; Bs[ac + 3][ar] = bv.w;
        __syncthreads();
#pragma unroll
        for (int k2 = 0; k2 < 16; k2++) {
            float4 a4 = *(const float4*)&As[k2][ty * 4];
            float4 b4 = *(const float4*)&Bs[k2][tx * 4];
            float a[4] = {a4.x, a4.y, a4.z, a4.w};
            float bb2[4] = {b4.x, b4.y, b4.z, b4.w};
#pragma unroll
            for (int r = 0; r < 4; r++)
#pragma unroll
                for (int c = 0; c < 4; c++) acc[r][c] += a[r] * bb2[c];
        }
        __syncthreads();
    }
#pragma unroll
    for (int r = 0; r < 4; r++) {
        int t = m0 + ty * 4 + r;
#pragma unroll
        for (int c = 0; c < 4; c++) {
            int cc = cbase + tx * 4 + c;
            out[(size_t)t * 768 + cc] = acc[r][c] + bias[cc];
        }
    }
}

// ---------------- LayerNorm pass: one block per token ----------------
__global__ __launch_bounds__(256) void k_ln(
    const float* __restrict__ in, const float* __restrict__ g,
    const float* __restrict__ beta, float* __restrict__ out)
{
    int blk = blockIdx.x;
    int tid = threadIdx.x;
    __shared__ float redA[256], redB[256];
    float v[3];
#pragma unroll
    for (int r = 0; r < 3; r++) v[r] = in[(size_t)blk * 768 + r * 256 + tid];
    float s = v[0] + v[1] + v[2];
    float sq = v[0] * v[0] + v[1] * v[1] + v[2] * v[2];
    redA[tid] = s; redB[tid] = sq;
    __syncthreads();
    for (int off = 128; off > 0; off >>= 1) {
        if (tid < off) { redA[tid] += redA[tid + off]; redB[tid] += redB[tid + off]; }
        __syncthreads();
    }
    float mu = redA[0] * (1.0f / 768.0f);
    float var = redB[0] * (1.0f / 768.0f) - mu * mu;
    float rstd = rsqrtf(var + 1e-5f);
#pragma unroll
    for (int r = 0; r < 3; r++) {
        int c = r * 256 + tid;
        out[(size_t)blk * 768 + c] = (v[r] - mu) * rstd * g[c] + beta[c];
    }
}

// ---------------- generic 64x64x16 fp32 tile GEMM: C = A*B^T + bias ----------------
__global__ __launch_bounds__(256) void k_gemm_abt_bias(
    const float* __restrict__ A, const float* __restrict__ B, const float* __restrict__ bias,
    float* __restrict__ C, int K, int lda, int ldb, int ldc)
{
    __shared__ float As[16][68];
    __shared__ float Bs[16][68];
    int tid = threadIdx.x;
    int m0 = blockIdx.y * 64, n0 = blockIdx.x * 64;
    int ar = tid >> 2, ac = (tid & 3) * 4;
    int ty = tid >> 4, tx = tid & 15;
    float acc[4][4] = {};
    for (int k0 = 0; k0 < K; k0 += 16) {
        float4 av = *(const float4*)(A + (size_t)(m0 + ar) * lda + k0 + ac);
        float4 bv = *(const float4*)(B + (size_t)(n0 + ar) * ldb + k0 + ac);
        As[ac + 0][ar] = av.x; As[ac + 1][ar] = av.y; As[ac + 2][ar] = av.z; As[ac + 3][ar] = av.w;
        Bs[ac + 0][ar] = bv.x; Bs[ac + 1][ar] = bv.y; Bs[ac + 2][ar] = bv.z; Bs[ac + 3][ar] = bv.w;
        __syncthreads();
#pragma unroll
        for (int k = 0; k < 16; k++) {
            float4 a4 = *(const float4*)&As[k][ty * 4];
            float4 b4 = *(const float4*)&Bs[k][tx * 4];
            float a[4] = {a4.x, a4.y, a4.z, a4.w};
            float bb2[4] = {b4.x, b4.y, b4.z, b4.w};
#pragma unroll
            for (int r = 0; r < 4; r++)
#pragma unroll
                for (int c = 0; c < 4; c++) acc[r][c] += a[r] * bb2[c];
        }
        __syncthreads();
    }
#pragma unroll
    for (int r = 0; r < 4; r++) {
        int mm = m0 + ty * 4 + r;
#pragma unroll
        for (int c = 0; c < 4; c++) {
            int nn = n0 + tx * 4 + c;
            C[(size_t)mm * ldc + nn] = acc[r][c] + bias[nn];
        }
    }
}

// ---------------- per-(w,h,l) inverse norms: rsqrt(||q96||^2 + 32) ----------------
__global__ __launch_bounds__(256) void k_norm(
    const float* __restrict__ qbuf, const float* __restrict__ bbuf,
    float* __restrict__ qinv, float* __restrict__ binv)
{
    int blk = blockIdx.x;
    int tid = threadIdx.x;
    int which = blk >> 13;
    int row = blk & 8191;                  // w*1024 + l
    const float* src = (which ? bbuf : qbuf) + (size_t)row * 768;
    float* dst = which ? binv : qinv;
    __shared__ float sq[768];
#pragma unroll
    for (int r = 0; r < 3; r++) { int c = r * 256 + tid; float vv = src[c]; sq[c] = vv * vv; }
    __syncthreads();
    if (tid < 8) {
        float s = 32.0f;
        const float* p = sq + tid * 96;
#pragma unroll
        for (int d = 0; d < 96; d++) s += p[d];
        int w = row >> 10, l = row & 1023;
        dst[(size_t)(w * 8 + tid) * 1024 + l] = rsqrtf(s);
    }
}

// ---------------- pack q: fp32 [w*1024+l][768] head-slices -> hi/lo bf16 [z][1024][96] ----------------
__global__ __launch_bounds__(256) void k_packq(
    const float* __restrict__ src, unsigned short* __restrict__ dh, unsigned short* __restrict__ dl)
{
    int idx = blockIdx.x * 256 + threadIdx.x;     // 64*1024*24 = 1572864 quads
    int dq = idx % 24;
    int rest = idx / 24;
    int l = rest & 1023, z = rest >> 10;
    int w = z >> 3, h = z & 7;
    float4 v = *(const float4*)(src + (size_t)((w << 10) + l) * 768 + h * 96 + dq * 4);
    us4 hv, lv; split4(v, hv, lv);
    size_t o = ((size_t)(z << 10) + l) * 96 + dq * 4;
    *(us4*)(dh + o) = hv;
    *(us4*)(dl + o) = lv;
}

// ---------------- pack b: hi/lo [z][1024][96] + transposed hi/lo [z][96][1024] ----------------
__global__ __launch_bounds__(256) void k_packb(
    const float* __restrict__ src, unsigned short* __restrict__ dh, unsigned short* __restrict__ dl,
    unsigned short* __restrict__ th, unsigned short* __restrict__ tl)
{
    __shared__ float T[128][97];
    int z = blockIdx.x >> 3, lt = blockIdx.x & 7;     // 64 z * 8 row-tiles of 128
    int w = z >> 3, h = z & 7;
    int tid = threadIdx.x;
#pragma unroll
    for (int rq = 0; rq < 12; rq++) {                 // 128*24 quads / 256 threads
        int q = rq * 256 + tid;
        int l = q / 24, dq = (q % 24) * 4;
        float4 v = *(const float4*)(src + (size_t)((w << 10) + lt * 128 + l) * 768 + h * 96 + dq);
        us4 hv, lv; split4(v, hv, lv);
        size_t o = ((size_t)(z << 10) + lt * 128 + l) * 96 + dq;
        *(us4*)(dh + o) = hv;
        *(us4*)(dl + o) = lv;
        T[l][dq + 0] = v.x; T[l][dq + 1] = v.y; T[l][dq + 2] = v.z; T[l][dq + 3] = v.w;
    }
    __syncthreads();
#pragma unroll
    for (int rq = 0; rq < 12; rq++) {                 // 96*32 quads / 256 threads
        int q = rq * 256 + tid;
        int d = q >> 5, lq = (q & 31) * 4;
        float4 v = make_float4(T[lq + 0][d], T[lq + 1][d], T[lq + 2][d], T[lq + 3][d]);
        us4 hv, lv; split4(v, hv, lv);
        size_t o = ((size_t)z * 96 + d) * 1024 + lt * 128 + lq;
        *(us4*)(th + o) = hv;
        *(us4*)(tl + o) = lv;
    }
}

// ================= MFMA attn: per (z) S = (Q*B^T + R) scaled; split-bf16 3-product =================
__device__ __forceinline__ void load_frags96(
    const unsigned short* __restrict__ qAh, const unsigned short* __restrict__ qAl,
    const unsigned short* __restrict__ bBh, const unsigned short* __restrict__ bBl,
    int arow, int brow, int ko,
    short8 afh[4], short8 afl[4], short8 bfh[4], short8 bfl[4])
{
#pragma unroll
    for (int mi = 0; mi < 4; mi++) {
        size_t ro = (size_t)(arow + mi * 16) * 96 + ko;
        afh[mi] = *(const short8*)(qAh + ro);
        afl[mi] = *(const short8*)(qAl + ro);
    }
#pragma unroll
    for (int ni = 0; ni < 4; ni++) {
        size_t ro = (size_t)(brow + ni * 16) * 96 + ko;
        bfh[ni] = *(const short8*)(bBh + ro);
        bfl[ni] = *(const short8*)(bBl + ro);
    }
}

__device__ __forceinline__ void mfma_block44(
    short8 afh[4], short8 afl[4], short8 bfh[4], short8 bfl[4], f32x4 acc[4][4])
{
#pragma unroll
    for (int mi = 0; mi < 4; mi++)
#pragma unroll
        for (int ni = 0; ni < 4; ni++) {
            f32x4 c = acc[mi][ni];
            c = __builtin_amdgcn_mfma_f32_16x16x32_bf16(afh[mi], bfh[ni], c, 0, 0, 0);
            c = __builtin_amdgcn_mfma_f32_16x16x32_bf16(afh[mi], bfl[ni], c, 0, 0, 0);
            c = __builtin_amdgcn_mfma_f32_16x16x32_bf16(afl[mi], bfh[ni], c, 0, 0, 0);
            acc[mi][ni] = c;
        }
}

__global__ __launch_bounds__(256) void k_attn_mfma(
    const unsigned short* __restrict__ qh_, const unsigned short* __restrict__ ql_,
    const unsigned short* __restrict__ bh_, const unsigned short* __restrict__ bl_,
    const float* __restrict__ qinv, const float* __restrict__ binv,
    const float* __restrict__ rs, float* __restrict__ attn)
{
    int z = blockIdx.z;
    int n0 = blockIdx.x * 128, m0 = blockIdx.y * 128;
    int tid = threadIdx.x;
    int lane = tid & 63, wid = tid >> 6;
    int wm = wid >> 1, wn = wid & 1;
    int lrow = lane & 15, lgrp = lane >> 4;

    size_t zoff = (size_t)z * 1024 * 96;
    const unsigned short* qAh = qh_ + zoff;
    const unsigned short* qAl = ql_ + zoff;
    const unsigned short* bBh = bh_ + zoff;
    const unsigned short* bBl = bl_ + zoff;

    int arow = m0 + wm * 64 + lrow;
    int brow = n0 + wn * 64 + lrow;

    f32x4 acc[4][4] = {};
    short8 afh0[4], afl0[4], bfh0[4], bfl0[4];
    short8 afh1[4], afl1[4], bfh1[4], bfl1[4];

    // K = 96: 3 k-tiles of 32, prefetch depth 1
    load_frags96(qAh, qAl, bBh, bBl, arow, brow, 0 + lgrp * 8, afh0, afl0, bfh0, bfl0);
    load_frags96(qAh, qAl, bBh, bBl, arow, brow, 32 + lgrp * 8, afh1, afl1, bfh1, bfl1);
    mfma_block44(afh0, afl0, bfh0, bfl0, acc);
    load_frags96(qAh, qAl, bBh, bBl, arow, brow, 64 + lgrp * 8, afh0, afl0, bfh0, bfl0);
    mfma_block44(afh1, afl1, bfh1, bfl1, acc);
    mfma_block44(afh0, afl0, bfh0, bfl0, acc);

    // epilogue: C[i][j] = (dot + R[dy][dx]) * qinv[i] * binv[j]
    float* Cz = attn + ((size_t)z << 20);
    const float* qiz = qinv + (z << 10);
    const float* biz = binv + (z << 10);
    int ibase = m0 + wm * 64 + lgrp * 4;
    int jbase = n0 + wn * 64 + lrow;

    float qv[16];
#pragma unroll
    for (int mi = 0; mi < 4; mi++)
#pragma unroll
        for (int r = 0; r < 4; r++) qv[mi * 4 + r] = qiz[ibase + mi * 16 + r];

#pragma unroll
    for (int ni = 0; ni < 4; ni++) {
        int j = jbase + ni * 16;
        float bj = biz[j];
        int jy = j >> 5, jx = j & 31;
#pragma unroll
        for (int mi = 0; mi < 4; mi++) {
#pragma unroll
            for (int r = 0; r < 4; r++) {
                int i = ibase + mi * 16 + r;
                int dy = (i >> 5) - jy + 31;
                int dx = (i & 31) - jx + 31;
                Cz[(size_t)i * 1024 + j] = (acc[mi][ni][r] + rs[dy * 63 + dx]) * qv[mi * 4 + r] * bj;
            }
        }
    }
}

// ================= MFMA out: per z O = S * B; M=1024 N=96 K=1024; split-bf16 =================
__device__ __forceinline__ void stage_cvt_write(
    unsigned short (*Ah)[40], unsigned short (*Al)[40], int srow, int skb,
    float4 a, float4 b, float4 c, float4 d)
{
    us4 h0, l0, h1, l1, h2, l2, h3, l3;
    split4(a, h0, l0); split4(b, h1, l1); split4(c, h2, l2); split4(d, h3, l3);
    *(us4*)&Ah[srow][skb + 0]  = h0; *(us4*)&Al[srow][skb + 0]  = l0;
    *(us4*)&Ah[srow][skb + 4]  = h1; *(us4*)&Al[srow][skb + 4]  = l1;
    *(us4*)&Ah[srow][skb + 8]  = h2; *(us4*)&Al[srow][skb + 8]  = l2;
    *(us4*)&Ah[srow][skb + 12] = h3; *(us4*)&Al[srow][skb + 12] = l3;
}

__global__ __launch_bounds__(256) void k_out_mfma(
    const float* __restrict__ attn, const unsigned short* __restrict__ bth,
    const unsigned short* __restrict__ btl, float* __restrict__ tok)
{
    __shared__ unsigned short AhS[2][128][40];
    __shared__ unsigned short AlS[2][128][40];
    int z = blockIdx.z, m0 = blockIdx.y * 128;
    int w = z >> 3, h = z & 7;
    int tid = threadIdx.x, lane = tid & 63, wid = tid >> 6;
    int lrow = lane & 15, lgrp = lane >> 4;

    const float* A = attn + ((size_t)z << 20) + (size_t)m0 * 1024;
    const unsigned short* Bh = bth + (size_t)z * 98304;   // [96][1024]
    const unsigned short* Bl = btl + (size_t)z * 98304;

    int srow = tid >> 1, skb = (tid & 1) * 16;
    const float* sp = A + (size_t)srow * 1024 + skb;

    f32x4 acc[2][6] = {};

    // prologue: stage k-tile 0
    float4 sv0 = *(const float4*)(sp + 0);
    float4 sv1 = *(const float4*)(sp + 4);
    float4 sv2 = *(const float4*)(sp + 8);
    float4 sv3 = *(const float4*)(sp + 12);
    stage_cvt_write(AhS[0], AlS[0], srow, skb, sv0, sv1, sv2, sv3);
    __syncthreads();

    for (int kt = 0; kt < 32; kt++) {
        int cur = kt & 1;
        if (kt < 31) {                       // issue next-tile global loads early
            const float* p = sp + (kt + 1) * 32;
            sv0 = *(const float4*)(p + 0);
            sv1 = *(const float4*)(p + 4);
            sv2 = *(const float4*)(p + 8);
            sv3 = *(const float4*)(p + 12);
        }
        short8 bfh[6], bfl[6];
#pragma unroll
        for (int ni = 0; ni < 6; ni++) {
            size_t o = (size_t)(ni * 16 + lrow) * 1024 + kt * 32 + lgrp * 8;
            bfh[ni] = *(const short8*)(Bh + o);
            bfl[ni] = *(const short8*)(Bl + o);
        }
        short8 afh[2], afl[2];
#pragma unroll
        for (int mi = 0; mi < 2; mi++) {
            int r = wid * 32 + mi * 16 + lrow;
            afh[mi] = *(const short8*)&AhS[cur][r][lgrp * 8];
            afl[mi] = *(const short8*)&AlS[cur][r][lgrp * 8];
        }
#pragma unroll
        for (int mi = 0; mi < 2; mi++)
#pragma unroll
            for (int ni = 0; ni < 6; ni++) {
                f32x4 c = acc[mi][ni];
                c = __builtin_amdgcn_mfma_f32_16x16x32_bf16(afh[mi], bfh[ni], c, 0, 0, 0);
                c = __builtin_amdgcn_mfma_f32_16x16x32_bf16(afh[mi], bfl[ni], c, 0, 0, 0);
                c = __builtin_amdgcn_mfma_f32_16x16x32_bf16(afl[mi], bfh[ni], c, 0, 0, 0);
                acc[mi][ni] = c;
            }
        if (kt < 31) stage_cvt_write(AhS[cur ^ 1], AlS[cur ^ 1], srow, skb, sv0, sv1, sv2, sv3);
        __syncthreads();
    }

    // epilogue: scatter to token layout
    int b = w >> 2, wm = (w >> 1) & 1, wn = w & 1;
#pragma unroll
    for (int mi = 0; mi < 2; mi++) {
#pragma unroll
        for (int r = 0; r < 4; r++) {
            int i = m0 + wid * 32 + mi * 16 + lgrp * 4 + r;
            int t = (b * 64 + wm * 32 + (i >> 5)) * 64 + wn * 32 + (i & 31);
            float* tp = tok + (size_t)t * 768 + h * 96;
#pragma unroll
            for (int ni = 0; ni < 6; ni++) tp[ni * 16 + lrow] = acc[mi][ni][r];
        }
    }
}

// ---------------- final proj: C = tok * projw^T + projb, scatter to (B,768,64,64) ----------------
__global__ __launch_bounds__(256) void k_proj(
    const float* __restrict__ tok, const float* __restrict__ pw,
    const float* __restrict__ pb, float* __restrict__ out0)
{
    __shared__ float As[16][68];
    __shared__ float Bs[16][68];
    int tid = threadIdx.x;
    int m0 = blockIdx.y * 64, n0 = blockIdx.x * 64;
    int ar = tid >> 2, ac = (tid & 3) * 4;
    int ty = tid >> 4, tx = tid & 15;
    float acc[4][4] = {};
    for (int k0 = 0; k0 < 768; k0 += 16) {
        float4 av = *(const float4*)(tok + (size_t)(m0 + ar) * 768 + k0 + ac);
        float4 bv = *(const float4*)(pw + (size_t)(n0 + ar) * 768 + k0 + ac);
        As[ac + 0][ar] = av.x; As[ac + 1][ar] = av.y; As[ac + 2][ar] = av.z; As[ac + 3][ar] = av.w;
        Bs[ac + 0][ar] = bv.x; Bs[ac + 1][ar] = bv.y; Bs[ac + 2][ar] = bv.z; Bs[ac + 3][ar] = bv.w;
        __syncthreads();
#pragma unroll
        for (int k = 0; k < 16; k++) {
            float4 a4 = *(const float4*)&As[k][ty * 4];
            float4 b4 = *(const float4*)&Bs[k][tx * 4];
            float a[4] = {a4.x, a4.y, a4.z, a4.w};
            float bb2[4] = {b4.x, b4.y, b4.z, b4.w};
#pragma unroll
            for (int r = 0; r < 4; r++)
#pragma unroll
                for (int c = 0; c < 4; c++) acc[r][c] += a[r] * bb2[c];
        }
        __syncthreads();
    }
#pragma unroll
    for (int r = 0; r < 4; r++) {
        int t = m0 + ty * 4 + r;
        int b = t >> 12, p = t & 4095;
#pragma unroll
        for (int c = 0; c < 4; c++) {
            int cc = n0 + tx * 4 + c;
            out0[(size_t)b * 3145728 + (size_t)cc * 4096 + p] = acc[r][c] + pb[cc];
        }
    }
}

extern "C" void kernel_launch(void* const* d_in, const int* in_sizes, int n_in,
                              void* d_out, int out_size, void* d_ws, size_t ws_size,
                              hipStream_t stream)
{
    const float* x   = (const float*)d_in[0];
    const float* ow  = (const float*)d_in[1];
    const float* ob  = (const float*)d_in[2];
    const float* rw  = (const float*)d_in[3];
    const float* rb  = (const float*)d_in[4];
    const float* pe  = (const float*)d_in[5];
    const float* nbg = (const float*)d_in[6];
    const float* nbb = (const float*)d_in[7];
    const float* nqg = (const float*)d_in[8];
    const float* nqb = (const float*)d_in[9];
    const float* qw  = (const float*)d_in[10];
    const float* qb  = (const float*)d_in[11];
    const float* bw  = (const float*)d_in[12];
    const float* bb  = (const float*)d_in[13];
    const float* pw  = (const float*)d_in[14];
    const float* pb  = (const float*)d_in[15];

    float* out0 = (float*)d_out;                 // (2,768,64,64) = 6291456
    float* attn = out0 + 6291456;                // (8,8,1024,1024) = 67108864

    float* ws   = (float*)d_ws;
    float* rx   = ws;                            // slot0: 6291456
    float* opb  = ws + 1 * 6291456;              // slot1: op, LayerNormed
    float* rpb  = ws + 2 * 6291456;              // slot2: rp, LayerNormed
    float* qbuf = ws + 3 * 6291456;              // slot3: q projection
    float* bbuf = ws + 4 * 6291456;              // slot4: b projection
    float* qinv = ws + 5 * 6291456;              // 65536
    float* binv = qinv + 65536;                  // 65536
    float* rs   = binv + 65536;                  // 3969
    float* tok  = rx;                            // reuse slot0 (rx dead after convs)
    float* rpre = qbuf;                          // pre-LN resize conv out
    float* opre = bbuf;                          // pre-LN origin conv out

    // packed bf16 hi/lo buffers reuse dead fp32 slots (each slot = 25165824 B = 2 x 12582912 B)
    unsigned short* qh  = (unsigned short*)rpb;   // slot2: dead after q GEMM
    unsigned short* ql  = qh + 6291456;
    unsigned short* bh2 = (unsigned short*)opb;   // slot1: dead after b GEMM
    unsigned short* bl2 = bh2 + 6291456;
    unsigned short* bth = (unsigned short*)qbuf;  // slot3: qbuf dead after k_norm + k_packq
    unsigned short* btl = bth + 6291456;

    k_resize<<<24576, 256, 0, stream>>>(x, rx);
    k_rsmall<<<16, 256, 0, stream>>>(rs);

    dim3 gc(12, 128);
    k_convr<<<gc, 256, 0, stream>>>(rx, rw, rb, pe, rpre);
    k_convo<<<gc, 256, 0, stream>>>(x, ow, ob, opre);
    k_ln<<<8192, 256, 0, stream>>>(rpre, nqg, nqb, rpb);
    k_ln<<<8192, 256, 0, stream>>>(opre, nbg, nbb, opb);

    dim3 g1(12, 128);
    k_gemm_abt_bias<<<g1, 256, 0, stream>>>(rpb, qw, qb, qbuf, 768, 768, 768, 768);
    k_gemm_abt_bias<<<g1, 256, 0, stream>>>(opb, bw, bb, bbuf, 768, 768, 768, 768);

    k_norm<<<16384, 256, 0, stream>>>(qbuf, bbuf, qinv, binv);

    // pack projections to split-bf16 (order matters: packq reads qbuf before packb overwrites slot3)
    k_packq<<<6144, 256, 0, stream>>>(qbuf, qh, ql);
    k_packb<<<512, 256, 0, stream>>>(bbuf, bh2, bl2, bth, btl);

    dim3 ga(8, 8, 64);      // n-tiles, m-tiles, z
    k_attn_mfma<<<ga, 256, 0, stream>>>(qh, ql, bh2, bl2, qinv, binv, rs, attn);

    dim3 go(1, 8, 64);      // N=96 single tile, 8 m-tiles, z
    k_out_mfma<<<go, 256, 0, stream>>>(attn, bth, btl, tok);

    k_proj<<<g1, 256, 0, stream>>>(tok, pw, pb, out0);
}

// Round 2
// 999.858 us; speedup vs baseline: 1.2396x; 1.0500x over previous
//
#include <hip/hip_runtime.h>
#include <hip/hip_bf16.h>
#include <math.h>

// ---------- problem constants ----------
// x (2,3,512,512); grid 64x64 tokens of 768 ch; 8 windows of 32x32=1024 tokens
// heads=8, HD=96, F=16, rope feat dim 64, ||feat||^2 = 32 exactly.

typedef __attribute__((ext_vector_type(8))) short short8;   // 8 bf16 (4 VGPRs)
typedef __attribute__((ext_vector_type(4))) float f32x4;    // MFMA accumulator
typedef __attribute__((ext_vector_type(4))) unsigned short us4;

// bf16 split helpers: v ~= hi + lo with ~16-bit effective mantissa
__device__ __forceinline__ unsigned short f2bf(float f) {
    unsigned u = __float_as_uint(f);
    return (unsigned short)((u + 0x7FFFu + ((u >> 16) & 1u)) >> 16);   // RNE
}
__device__ __forceinline__ float bf2f(unsigned short h) { return __uint_as_float(((unsigned)h) << 16); }
__device__ __forceinline__ void split4(float4 v, us4& h4, us4& l4) {
    unsigned short h0 = f2bf(v.x), h1 = f2bf(v.y), h2 = f2bf(v.z), h3 = f2bf(v.w);
    h4 = (us4){h0, h1, h2, h3};
    l4 = (us4){f2bf(v.x - bf2f(h0)), f2bf(v.y - bf2f(h1)),
               f2bf(v.z - bf2f(h2)), f2bf(v.w - bf2f(h3))};
}

// ---------------- bilinear 2x resize (clamp-to-edge == jax renormalized) ----------------
__global__ __launch_bounds__(256) void k_resize(const float* __restrict__ x, float* __restrict__ rx)
{
    int idx = blockIdx.x * 256 + threadIdx.x;           // < 6291456 exactly
    int X = idx & 1023;
    int Y = (idx >> 10) & 1023;
    int bc = idx >> 20;                                 // 0..5 (b*3+c)
    float sy = Y * 0.5f - 0.25f;
    float sx = X * 0.5f - 0.25f;
    int y0 = (int)floorf(sy), x0 = (int)floorf(sx);
    float fy = sy - (float)y0, fx = sx - (float)x0;
    int y1 = y0 + 1, x1 = x0 + 1;
    y0 = max(0, min(511, y0)); y1 = max(0, min(511, y1));
    x0 = max(0, min(511, x0)); x1 = max(0, min(511, x1));
    const float* p = x + (size_t)bc * (512 * 512);
    float v00 = p[y0 * 512 + x0], v01 = p[y0 * 512 + x1];
    float v10 = p[y1 * 512 + x0], v11 = p[y1 * 512 + x1];
    rx[idx] = (1.f - fy) * ((1.f - fx) * v00 + fx * v01) + fy * ((1.f - fx) * v10 + fx * v11);
}

// ---------------- rope relative table R[dy+31][dx+31] ----------------
__global__ void k_rsmall(float* __restrict__ rs)
{
    int e = blockIdx.x * 256 + threadIdx.x;
    if (e >= 63 * 63) return;
    float dy = (float)(e / 63 - 31);
    float dx = (float)(e % 63 - 31);
    float s = 0.f;
    for (int f = 0; f < 16; f++) {
        float invf = powf(10.0f, -(float)f / 16.0f);
        s += cosf(dx * invf) + cosf(dy * invf);
    }
    rs[e] = s;
}

// ---------------- resize conv as tile GEMM: tokens(8192) x K(256) x ch(768, 3 groups) ----------------
__global__ __launch_bounds__(256) void k_convr(
    const float* __restrict__ rx, const float* __restrict__ wgt,
    const float* __restrict__ bias, const float* __restrict__ pe,
    float* __restrict__ out)
{
    __shared__ float As[16][68];
    __shared__ float Bs[16][68];
    int tid = threadIdx.x;
    int m0 = blockIdx.y * 64;         // token tile
    int cbase = blockIdx.x * 64;      // channel tile (stays within one group: 256%64==0)
    int ic = cbase >> 8;              // input channel for this group
    int ar = tid >> 2, ac = (tid & 3) * 4;
    int ty = tid >> 4, tx = tid & 15;

    int mtok = m0 + ar;
    int w = mtok >> 10, l = mtok & 1023;
    int b = w >> 2, wm = (w >> 1) & 1, wn = w & 1;
    int gy = wm * 32 + (l >> 5), gx = wn * 32 + (l & 31);
    const float* abase = rx + ((size_t)(b * 3 + ic) * 1024 + gy * 16) * 1024 + gx * 16;
    const float* bbase = wgt + (size_t)(cbase + ar) * 256;

    float acc[4][4] = {};
    for (int k0 = 0; k0 < 256; k0 += 16) {
        float4 av = *(const float4*)(abase + (size_t)(k0 >> 4) * 1024 + ac);
        float4 bv = *(const float4*)(bbase + k0 + ac);
        As[ac + 0][ar] = av.x; As[ac + 1][ar] = av.y; As[ac + 2][ar] = av.z; As[ac + 3][ar] = av.w;
        Bs[ac + 0][ar] = bv.x; Bs[ac + 1][ar] = bv.y; Bs[ac + 2][ar] = bv.z; Bs[ac + 3][ar] = bv.w;
        __syncthreads();
#pragma unroll
        for (int k = 0; k < 16; k++) {
            float4 a4 = *(const float4*)&As[k][ty * 4];
            float4 b4 = *(const float4*)&Bs[k][tx * 4];
            float a[4] = {a4.x, a4.y, a4.z, a4.w};
            float bb2[4] = {b4.x, b4.y, b4.z, b4.w};
#pragma unroll
            for (int r = 0; r < 4; r++)
#pragma unroll
                for (int c = 0; c < 4; c++) acc[r][c] += a[r] * bb2[c];
        }
        __syncthreads();
    }
#pragma unroll
    for (int r = 0; r < 4; r++) {
        int t = m0 + ty * 4 + r;
        int tw = t >> 10, tl = t & 1023;
        int tgy = ((tw >> 1) & 1) * 32 + (tl >> 5);
        int tgx = (tw & 1) * 32 + (tl & 31);
#pragma unroll
        for (int c = 0; c < 4; c++) {
            int cc = cbase + tx * 4 + c;
            out[(size_t)t * 768 + cc] = acc[r][c] + bias[cc] + pe[(size_t)cc * 4096 + tgy * 64 + tgx];
        }
    }
}

// ---------------- origin conv as tile GEMM: tokens(8192) x K(64) x ch(768, 3 groups) ----------------
__global__ __launch_bounds__(256) void k_convo(
    const float* __restrict__ x, const float* __restrict__ wgt,
    const float* __restrict__ bias, float* __restrict__ out)
{
    __shared__ float As[16][68];
    __shared__ float Bs[16][68];
    int tid = threadIdx.x;
    int m0 = blockIdx.y * 64;
    int cbase = blockIdx.x * 64;
    int ic = cbase >> 8;
    int ar = tid >> 2, ac = (tid & 3) * 4;
    int ty = tid >> 4, tx = tid & 15;

    int mtok = m0 + ar;
    int w = mtok >> 10, l = mtok & 1023;
    int b = w >> 2, wm = (w >> 1) & 1, wn = w & 1;
    int gy = wm * 32 + (l >> 5), gx = wn * 32 + (l & 31);
    const float* abase = x + ((size_t)(b * 3 + ic) * 512 + gy * 8) * 512 + gx * 8;
    const float* bbase = wgt + (size_t)(cbase + ar) * 64;

    float acc[4][4] = {};
    for (int k0 = 0; k0 < 64; k0 += 16) {
        int k = k0 + ac;
        float4 av = *(const float4*)(abase + (size_t)(k >> 3) * 512 + (k & 7));
        float4 bv = *(const float4*)(bbase + k);
        As[ac + 0][ar] = av.x; As[ac + 1][ar] = av.y; As[ac + 2][ar] = av.z; As[ac + 3][ar] = av.w;
        Bs[ac + 0][ar] = bv.x; Bs[ac + 1][ar] = bv.y; Bs[ac + 2][ar] = bv.z; Bs[ac + 3][ar] = bv.w;
        __syncthreads();
#pragma unroll
        for (int k2 = 0; k2 < 16; k2++) {
            float4 a4 = *(const float4*)&As[k2][ty * 4];
            float4 b4 = *(const float4*)&Bs[k2][tx * 4];
            float a[4] = {a4.x, a4.y, a4.z, a4.w};
            float bb2[4] = {b4.x, b4.y, b4.z, b4.w};
#pragma unroll
            for (int r = 0; r < 4; r++)
#pragma unroll
                for (int c = 0; c < 4; c++) acc[r][c] += a[r] * bb2[c];
        }
        __syncthreads();
    }
#pragma unroll
    for (int r = 0; r < 4; r++) {
        int t = m0 + ty * 4 + r;
#pragma unroll
        for (int c = 0; c < 4; c++) {
            int cc = cbase + tx * 4 + c;
            out[(size_t)t * 768 + cc] = acc[r][c] + bias[cc];
        }
    }
}

// ---------------- LayerNorm fused with split-bf16 pack: one block per token ----------------
__global__ __launch_bounds__(256) void k_ln_pack(
    const float* __restrict__ in, const float* __restrict__ g,
    const float* __restrict__ beta, unsigned short* __restrict__ oh,
    unsigned short* __restrict__ ol)
{
    int blk = blockIdx.x;
    int tid = threadIdx.x;
    __shared__ float redA[256], redB[256];
    float v[3];
#pragma unroll
    for (int r = 0; r < 3; r++) v[r] = in[(size_t)blk * 768 + r * 256 + tid];
    float s = v[0] + v[1] + v[2];
    float sq = v[0] * v[0] + v[1] * v[1] + v[2] * v[2];
    redA[tid] = s; redB[tid] = sq;
    __syncthreads();
    for (int off = 128; off > 0; off >>= 1) {
        if (tid < off) { redA[tid] += redA[tid + off]; redB[tid] += redB[tid + off]; }
        __syncthreads();
    }
    float mu = redA[0] * (1.0f / 768.0f);
    float var = redB[0] * (1.0f / 768.0f) - mu * mu;
    float rstd = rsqrtf(var + 1e-5f);
#pragma unroll
    for (int r = 0; r < 3; r++) {
        int c = r * 256 + tid;
        float y = (v[r] - mu) * rstd * g[c] + beta[c];
        unsigned short hv = f2bf(y);
        oh[(size_t)blk * 768 + c] = hv;
        ol[(size_t)blk * 768 + c] = f2bf(y - bf2f(hv));
    }
}

// ---------------- generic fp32 -> split-bf16 weight pack ----------------
__global__ __launch_bounds__(256) void k_packw(
    const float* __restrict__ src, unsigned short* __restrict__ dh,
    unsigned short* __restrict__ dl, int n4)
{
    int idx = blockIdx.x * 256 + threadIdx.x;
    if (idx >= n4) return;
    float4 v = ((const float4*)src)[idx];
    us4 h, l; split4(v, h, l);
    ((us4*)dh)[idx] = h;
    ((us4*)dl)[idx] = l;
}

// ---------------- per-(w,h,l) inverse norms: rsqrt(||q96||^2 + 32) ----------------
__global__ __launch_bounds__(256) void k_norm(
    const float* __restrict__ qbuf, const float* __restrict__ bbuf,
    float* __restrict__ qinv, float* __restrict__ binv)
{
    int blk = blockIdx.x;
    int tid = threadIdx.x;
    int which = blk >> 13;
    int row = blk & 8191;                  // w*1024 + l
    const float* src = (which ? bbuf : qbuf) + (size_t)row * 768;
    float* dst = which ? binv : qinv;
    __shared__ float sq[768];
#pragma unroll
    for (int r = 0; r < 3; r++) { int c = r * 256 + tid; float vv = src[c]; sq[c] = vv * vv; }
    __syncthreads();
    if (tid < 8) {
        float s = 32.0f;
        const float* p = sq + tid * 96;
#pragma unroll
        for (int d = 0; d < 96; d++) s += p[d];
        int w = row >> 10, l = row & 1023;
        dst[(size_t)(w * 8 + tid) * 1024 + l] = rsqrtf(s);
    }
}

// ---------------- pack q: fp32 [w*1024+l][768] head-slices -> hi/lo bf16 [z][1024][96] ----------------
__global__ __launch_bounds__(256) void k_packq(
    const float* __restrict__ src, unsigned short* __restrict__ dh, unsigned short* __restrict__ dl)
{
    int idx = blockIdx.x * 256 + threadIdx.x;     // 64*1024*24 = 1572864 quads
    int dq = idx % 24;
    int rest = idx / 24;
    int l = rest & 1023, z = rest >> 10;
    int w = z >> 3, h = z & 7;
    float4 v = *(const float4*)(src + (size_t)((w << 10) + l) * 768 + h * 96 + dq * 4);
    us4 hv, lv; split4(v, hv, lv);
    size_t o = ((size_t)(z << 10) + l) * 96 + dq * 4;
    *(us4*)(dh + o) = hv;
    *(us4*)(dl + o) = lv;
}

// ---------------- pack b: hi/lo [z][1024][96] + transposed hi/lo [z][96][1024] ----------------
__global__ __launch_bounds__(256) void k_packb(
    const float* __restrict__ src, unsigned short* __restrict__ dh, unsigned short* __restrict__ dl,
    unsigned short* __restrict__ th, unsigned short* __restrict__ tl)
{
    __shared__ float T[128][97];
    int z = blockIdx.x >> 3, lt = blockIdx.x & 7;     // 64 z * 8 row-tiles of 128
    int w = z >> 3, h = z & 7;
    int tid = threadIdx.x;
#pragma unroll
    for (int rq = 0; rq < 12; rq++) {                 // 128*24 quads / 256 threads
        int q = rq * 256 + tid;
        int l = q / 24, dq = (q % 24) * 4;
        float4 v = *(const float4*)(src + (size_t)((w << 10) + lt * 128 + l) * 768 + h * 96 + dq);
        us4 hv, lv; split4(v, hv, lv);
        size_t o = ((size_t)(z << 10) + lt * 128 + l) * 96 + dq;
        *(us4*)(dh + o) = hv;
        *(us4*)(dl + o) = lv;
        T[l][dq + 0] = v.x; T[l][dq + 1] = v.y; T[l][dq + 2] = v.z; T[l][dq + 3] = v.w;
    }
    __syncthreads();
#pragma unroll
    for (int rq = 0; rq < 12; rq++) {                 // 96*32 quads / 256 threads
        int q = rq * 256 + tid;
        int d = q >> 5, lq = (q & 31) * 4;
        float4 v = make_float4(T[lq + 0][d], T[lq + 1][d], T[lq + 2][d], T[lq + 3][d]);
        us4 hv, lv; split4(v, hv, lv);
        size_t o = ((size_t)z * 96 + d) * 1024 + lt * 128 + lq;
        *(us4*)(th + o) = hv;
        *(us4*)(tl + o) = lv;
    }
}

// ---------------- shared MFMA helpers ----------------
__device__ __forceinline__ void mfma_block44(
    short8 afh[4], short8 afl[4], short8 bfh[4], short8 bfl[4], f32x4 acc[4][4])
{
#pragma unroll
    for (int mi = 0; mi < 4; mi++)
#pragma unroll
        for (int ni = 0; ni < 4; ni++) {
            f32x4 c = acc[mi][ni];
            c = __builtin_amdgcn_mfma_f32_16x16x32_bf16(afh[mi], bfh[ni], c, 0, 0, 0);
            c = __builtin_amdgcn_mfma_f32_16x16x32_bf16(afh[mi], bfl[ni], c, 0, 0, 0);
            c = __builtin_amdgcn_mfma_f32_16x16x32_bf16(afl[mi], bfh[ni], c, 0, 0, 0);
            acc[mi][ni] = c;
        }
}

// 128x128 tile, K=768, A [*,768] hi/lo, B [*,768] hi/lo (both k-contiguous), register-direct
__device__ __forceinline__ void gemm768_core(
    const unsigned short* __restrict__ Ah, const unsigned short* __restrict__ Al,
    const unsigned short* __restrict__ Bh, const unsigned short* __restrict__ Bl,
    int arow, int brow, int lgrp, f32x4 acc[4][4])
{
    short8 afh0[4], afl0[4], bfh0[4], bfl0[4];
    short8 afh1[4], afl1[4], bfh1[4], bfl1[4];
    auto LD = [&](short8 afh[4], short8 afl[4], short8 bfh[4], short8 bfl[4], int kt) {
#pragma unroll
        for (int mi = 0; mi < 4; mi++) {
            size_t ro = (size_t)(arow + mi * 16) * 768 + kt * 32 + lgrp * 8;
            afh[mi] = *(const short8*)(Ah + ro);
            afl[mi] = *(const short8*)(Al + ro);
        }
#pragma unroll
        for (int ni = 0; ni < 4; ni++) {
            size_t ro = (size_t)(brow + ni * 16) * 768 + kt * 32 + lgrp * 8;
            bfh[ni] = *(const short8*)(Bh + ro);
            bfl[ni] = *(const short8*)(Bl + ro);
        }
    };
    LD(afh0, afl0, bfh0, bfl0, 0);
#pragma unroll 1
    for (int kt = 0; kt < 24; kt += 2) {
        LD(afh1, afl1, bfh1, bfl1, kt + 1);
        mfma_block44(afh0, afl0, bfh0, bfl0, acc);
        if (kt + 2 < 24) LD(afh0, afl0, bfh0, bfl0, kt + 2);
        mfma_block44(afh1, afl1, bfh1, bfl1, acc);
    }
}

// ---------------- MFMA GEMM: C[M=8192][768] = A * B^T + bias ----------------
__global__ __launch_bounds__(256) void k_gemm_mfma_bias(
    const unsigned short* __restrict__ Ah, const unsigned short* __restrict__ Al,
    const unsigned short* __restrict__ Bh, const unsigned short* __restrict__ Bl,
    const float* __restrict__ bias, float* __restrict__ C)
{
    int tid = threadIdx.x, lane = tid & 63, wid = tid >> 6;
    int wm = wid >> 1, wn = wid & 1;
    int lrow = lane & 15, lgrp = lane >> 4;
    int m0 = blockIdx.y * 128, n0 = blockIdx.x * 128;
    int arow = m0 + wm * 64 + lrow;
    int brow = n0 + wn * 64 + lrow;
    f32x4 acc[4][4] = {};
    gemm768_core(Ah, Al, Bh, Bl, arow, brow, lgrp, acc);

    int ibase = m0 + wm * 64 + lgrp * 4;
    int jbase = n0 + wn * 64 + lrow;
#pragma unroll
    for (int ni = 0; ni < 4; ni++) {
        int j = jbase + ni * 16;
        float bj = bias[j];
#pragma unroll
        for (int mi = 0; mi < 4; mi++) {
            int ib = ibase + mi * 16;
#pragma unroll
            for (int r = 0; r < 4; r++)
                C[(size_t)(ib + r) * 768 + j] = acc[mi][ni][r] + bj;
        }
    }
}

// ---------------- MFMA proj: out0[b][cc][p] = tok * projw^T + projb ----------------
__global__ __launch_bounds__(256) void k_proj_mfma(
    const unsigned short* __restrict__ Ah, const unsigned short* __restrict__ Al,
    const unsigned short* __restrict__ Bh, const unsigned short* __restrict__ Bl,
    const float* __restrict__ pb, float* __restrict__ out0)
{
    int tid = threadIdx.x, lane = tid & 63, wid = tid >> 6;
    int wm = wid >> 1, wn = wid & 1;
    int lrow = lane & 15, lgrp = lane >> 4;
    int m0 = blockIdx.y * 128, n0 = blockIdx.x * 128;
    int arow = m0 + wm * 64 + lrow;
    int brow = n0 + wn * 64 + lrow;
    f32x4 acc[4][4] = {};
    gemm768_core(Ah, Al, Bh, Bl, arow, brow, lgrp, acc);

    int ibase = m0 + wm * 64 + lgrp * 4;
    int jbase = n0 + wn * 64 + lrow;
#pragma unroll
    for (int ni = 0; ni < 4; ni++) {
        int cc = jbase + ni * 16;
        float bj = pb[cc];
        float* obase = out0 + (size_t)cc * 4096;
#pragma unroll
        for (int mi = 0; mi < 4; mi++) {
            int i0 = ibase + mi * 16;           // 4 consecutive token rows i0..i0+3
            float4 v = make_float4(acc[mi][ni][0] + bj, acc[mi][ni][1] + bj,
                                   acc[mi][ni][2] + bj, acc[mi][ni][3] + bj);
            *(float4*)(obase + (size_t)(i0 >> 12) * 3145728 + (i0 & 4095)) = v;
        }
    }
}

// ================= MFMA attn: per (z) S = (Q*B^T + R) scaled; split-bf16 3-product =================
__device__ __forceinline__ void load_frags96(
    const unsigned short* __restrict__ qAh, const unsigned short* __restrict__ qAl,
    const unsigned short* __restrict__ bBh, const unsigned short* __restrict__ bBl,
    int arow, int brow, int ko,
    short8 afh[4], short8 afl[4], short8 bfh[4], short8 bfl[4])
{
#pragma unroll
    for (int mi = 0; mi < 4; mi++) {
        size_t ro = (size_t)(arow + mi * 16) * 96 + ko;
        afh[mi] = *(const short8*)(qAh + ro);
        afl[mi] = *(const short8*)(qAl + ro);
    }
#pragma unroll
    for (int ni = 0; ni < 4; ni++) {
        size_t ro = (size_t)(brow + ni * 16) * 96 + ko;
        bfh[ni] = *(const short8*)(bBh + ro);
        bfl[ni] = *(const short8*)(bBl + ro);
    }
}

__global__ __launch_bounds__(256) void k_attn_mfma(
    const unsigned short* __restrict__ qh_, const unsigned short* __restrict__ ql_,
    const unsigned short* __restrict__ bh_, const unsigned short* __restrict__ bl_,
    const float* __restrict__ qinv, const float* __restrict__ binv,
    const float* __restrict__ rs, float* __restrict__ attn)
{
    int z = blockIdx.z;
    int n0 = blockIdx.x * 128, m0 = blockIdx.y * 128;
    int tid = threadIdx.x;
    int lane = tid & 63, wid = tid >> 6;
    int wm = wid >> 1, wn = wid & 1;
    int lrow = lane & 15, lgrp = lane >> 4;

    size_t zoff = (size_t)z * 1024 * 96;
    const unsigned short* qAh = qh_ + zoff;
    const unsigned short* qAl = ql_ + zoff;
    const unsigned short* bBh = bh_ + zoff;
    const unsigned short* bBl = bl_ + zoff;

    int arow = m0 + wm * 64 + lrow;
    int brow = n0 + wn * 64 + lrow;

    f32x4 acc[4][4] = {};
    short8 afh0[4], afl0[4], bfh0[4], bfl0[4];
    short8 afh1[4], afl1[4], bfh1[4], bfl1[4];

    // K = 96: 3 k-tiles of 32, prefetch depth 1
    load_frags96(qAh, qAl, bBh, bBl, arow, brow, 0 + lgrp * 8, afh0, afl0, bfh0, bfl0);
    load_frags96(qAh, qAl, bBh, bBl, arow, brow, 32 + lgrp * 8, afh1, afl1, bfh1, bfl1);
    mfma_block44(afh0, afl0, bfh0, bfl0, acc);
    load_frags96(qAh, qAl, bBh, bBl, arow, brow, 64 + lgrp * 8, afh0, afl0, bfh0, bfl0);
    mfma_block44(afh1, afl1, bfh1, bfl1, acc);
    mfma_block44(afh0, afl0, bfh0, bfl0, acc);

    // epilogue: C[i][j] = (dot + R[dy][dx]) * qinv[i] * binv[j]
    float* Cz = attn + ((size_t)z << 20);
    const float* qiz = qinv + (z << 10);
    const float* biz = binv + (z << 10);
    int ibase = m0 + wm * 64 + lgrp * 4;
    int jbase = n0 + wn * 64 + lrow;

    float qv[16];
#pragma unroll
    for (int mi = 0; mi < 4; mi++)
#pragma unroll
        for (int r = 0; r < 4; r++) qv[mi * 4 + r] = qiz[ibase + mi * 16 + r];

#pragma unroll
    for (int ni = 0; ni < 4; ni++) {
        int j = jbase + ni * 16;
        float bj = biz[j];
        int jy = j >> 5, jx = j & 31;
#pragma unroll
        for (int mi = 0; mi < 4; mi++) {
#pragma unroll
            for (int r = 0; r < 4; r++) {
                int i = ibase + mi * 16 + r;
                int dy = (i >> 5) - jy + 31;
                int dx = (i & 31) - jx + 31;
                Cz[(size_t)i * 1024 + j] = (acc[mi][ni][r] + rs[dy * 63 + dx]) * qv[mi * 4 + r] * bj;
            }
        }
    }
}

// ================= MFMA out: per z O = S * B; M=1024 N=96 K=1024; split-bf16 =================
__device__ __forceinline__ void stage_cvt_write(
    unsigned short (*Ah)[40], unsigned short (*Al)[40], int srow, int skb,
    float4 a, float4 b, float4 c, float4 d)
{
    us4 h0, l0, h1, l1, h2, l2, h3, l3;
    split4(a, h0, l0); split4(b, h1, l1); split4(c, h2, l2); split4(d, h3, l3);
    *(us4*)&Ah[srow][skb + 0]  = h0; *(us4*)&Al[srow][skb + 0]  = l0;
    *(us4*)&Ah[srow][skb + 4]  = h1; *(us4*)&Al[srow][skb + 4]  = l1;
    *(us4*)&Ah[srow][skb + 8]  = h2; *(us4*)&Al[srow][skb + 8]  = l2;
    *(us4*)&Ah[srow][skb + 12] = h3; *(us4*)&Al[srow][skb + 12] = l3;
}

__global__ __launch_bounds__(256) void k_out_mfma(
    const float* __restrict__ attn, const unsigned short* __restrict__ bth,
    const unsigned short* __restrict__ btl, unsigned short* __restrict__ tokh,
    unsigned short* __restrict__ tokl)
{
    __shared__ unsigned short AhS[2][128][40];
    __shared__ unsigned short AlS[2][128][40];
    int z = blockIdx.z, m0 = blockIdx.y * 128;
    int w = z >> 3, h = z & 7;
    int tid = threadIdx.x, lane = tid & 63, wid = tid >> 6;
    int lrow = lane & 15, lgrp = lane >> 4;

    const float* A = attn + ((size_t)z << 20) + (size_t)m0 * 1024;
    const unsigned short* Bh = bth + (size_t)z * 98304;   // [96][1024]
    const unsigned short* Bl = btl + (size_t)z * 98304;

    int srow = tid >> 1, skb = (tid & 1) * 16;
    const float* sp = A + (size_t)srow * 1024 + skb;

    f32x4 acc[2][6] = {};

    // prologue: stage k-tile 0
    float4 sv0 = *(const float4*)(sp + 0);
    float4 sv1 = *(const float4*)(sp + 4);
    float4 sv2 = *(const float4*)(sp + 8);
    float4 sv3 = *(const float4*)(sp + 12);
    stage_cvt_write(AhS[0], AlS[0], srow, skb, sv0, sv1, sv2, sv3);
    __syncthreads();

    for (int kt = 0; kt < 32; kt++) {
        int cur = kt & 1;
        if (kt < 31) {                       // issue next-tile global loads early
            const float* p = sp + (kt + 1) * 32;
            sv0 = *(const float4*)(p + 0);
            sv1 = *(const float4*)(p + 4);
            sv2 = *(const float4*)(p + 8);
            sv3 = *(const float4*)(p + 12);
        }
        short8 bfh[6], bfl[6];
#pragma unroll
        for (int ni = 0; ni < 6; ni++) {
            size_t o = (size_t)(ni * 16 + lrow) * 1024 + kt * 32 + lgrp * 8;
            bfh[ni] = *(const short8*)(Bh + o);
            bfl[ni] = *(const short8*)(Bl + o);
        }
        short8 afh[2], afl[2];
#pragma unroll
        for (int mi = 0; mi < 2; mi++) {
            int r = wid * 32 + mi * 16 + lrow;
            afh[mi] = *(const short8*)&AhS[cur][r][lgrp * 8];
            afl[mi] = *(const short8*)&AlS[cur][r][lgrp * 8];
        }
#pragma unroll
        for (int mi = 0; mi < 2; mi++)
#pragma unroll
            for (int ni = 0; ni < 6; ni++) {
                f32x4 c = acc[mi][ni];
                c = __builtin_amdgcn_mfma_f32_16x16x32_bf16(afh[mi], bfh[ni], c, 0, 0, 0);
                c = __builtin_amdgcn_mfma_f32_16x16x32_bf16(afh[mi], bfl[ni], c, 0, 0, 0);
                c = __builtin_amdgcn_mfma_f32_16x16x32_bf16(afl[mi], bfh[ni], c, 0, 0, 0);
                acc[mi][ni] = c;
            }
        if (kt < 31) stage_cvt_write(AhS[cur ^ 1], AlS[cur ^ 1], srow, skb, sv0, sv1, sv2, sv3);
        __syncthreads();
    }

    // epilogue: scatter split-bf16 to token layout (consumed by proj MFMA)
    int b = w >> 2, wm = (w >> 1) & 1, wn = w & 1;
#pragma unroll
    for (int mi = 0; mi < 2; mi++) {
#pragma unroll
        for (int r = 0; r < 4; r++) {
            int i = m0 + wid * 32 + mi * 16 + lgrp * 4 + r;
            int t = (b * 64 + wm * 32 + (i >> 5)) * 64 + wn * 32 + (i & 31);
            size_t base = (size_t)t * 768 + h * 96;
#pragma unroll
            for (int ni = 0; ni < 6; ni++) {
                float v = acc[mi][ni][r];
                unsigned short hv = f2bf(v);
                tokh[base + ni * 16 + lrow] = hv;
                tokl[base + ni * 16 + lrow] = f2bf(v - bf2f(hv));
            }
        }
    }
}

extern "C" void kernel_launch(void* const* d_in, const int* in_sizes, int n_in,
                              void* d_out, int out_size, void* d_ws, size_t ws_size,
                              hipStream_t stream)
{
    const float* x   = (const float*)d_in[0];
    const float* ow  = (const float*)d_in[1];
    const float* ob  = (const float*)d_in[2];
    const float* rw  = (const float*)d_in[3];
    const float* rb  = (const float*)d_in[4];
    const float* pe  = (const float*)d_in[5];
    const float* nbg = (const float*)d_in[6];
    const float* nbb = (const float*)d_in[7];
    const float* nqg = (const float*)d_in[8];
    const float* nqb = (const float*)d_in[9];
    const float* qw  = (const float*)d_in[10];
    const float* qb  = (const float*)d_in[11];
    const float* bw  = (const float*)d_in[12];
    const float* bb  = (const float*)d_in[13];
    const float* pw  = (const float*)d_in[14];
    const float* pb  = (const float*)d_in[15];

    float* out0 = (float*)d_out;                 // (2,768,64,64) = 6291456
    float* attn = out0 + 6291456;                // (8,8,1024,1024) = 67108864

    float* ws   = (float*)d_ws;
    float* rx   = ws;                            // slot0
    float* slot1 = ws + 1 * 6291456;
    float* slot2 = ws + 2 * 6291456;
    float* slot3 = ws + 3 * 6291456;
    float* slot4 = ws + 4 * 6291456;
    float* qinv = ws + 5 * 6291456;              // 65536
    float* binv = qinv + 65536;                  // 65536
    float* rs   = binv + 65536;                  // 3969

    float* rpre = slot3;                         // pre-LN resize conv out
    float* opre = slot4;                         // pre-LN origin conv out
    float* qbuf = slot3;                         // q projection fp32 (overwrites rpre)
    float* bbuf = slot4;                         // b projection fp32 (overwrites opre)

    // LN'd activations, split-bf16 (each slot = 25165824 B = 2 x 12582912 B)
    unsigned short* rlnh = (unsigned short*)slot2;
    unsigned short* rlnl = rlnh + 6291456;
    unsigned short* olnh = (unsigned short*)slot1;
    unsigned short* olnl = olnh + 6291456;

    // packed weights: qw/bw in slot0 (rx dead after convr; dead before k_out writes tok)
    unsigned short* qwh = (unsigned short*)rx;
    unsigned short* qwl = qwh + 589824;
    unsigned short* bwh = qwh + 2 * 589824;
    unsigned short* bwl = qwh + 3 * 589824;
    // projw packed in slot4 (bbuf dead after packb)
    unsigned short* pwh = (unsigned short*)slot4;
    unsigned short* pwl = pwh + 589824;

    // per-head packed q/b (overwrite dead LN buffers)
    unsigned short* qh  = (unsigned short*)slot2;   // after q GEMM, rln dead
    unsigned short* ql  = qh + 6291456;
    unsigned short* bh2 = (unsigned short*)slot1;   // after b GEMM, oln dead
    unsigned short* bl2 = bh2 + 6291456;
    unsigned short* bth = (unsigned short*)slot3;   // after norm+packq, qbuf dead
    unsigned short* btl = bth + 6291456;

    // tok split-bf16 in slot0 (qw/bw packs dead after b GEMM)
    unsigned short* tokh = (unsigned short*)rx;
    unsigned short* tokl = tokh + 6291456;

    k_resize<<<24576, 256, 0, stream>>>(x, rx);
    k_rsmall<<<16, 256, 0, stream>>>(rs);

    dim3 gc(12, 128);
    k_convr<<<gc, 256, 0, stream>>>(rx, rw, rb, pe, rpre);
    // rx dead now: pack q/b weights into slot0
    k_packw<<<576, 256, 0, stream>>>(qw, qwh, qwl, 147456);
    k_packw<<<576, 256, 0, stream>>>(bw, bwh, bwl, 147456);
    k_convo<<<gc, 256, 0, stream>>>(x, ow, ob, opre);

    k_ln_pack<<<8192, 256, 0, stream>>>(rpre, nqg, nqb, rlnh, rlnl);
    k_ln_pack<<<8192, 256, 0, stream>>>(opre, nbg, nbb, olnh, olnl);

    dim3 gg(6, 64);     // N=768/128, M=8192/128
    k_gemm_mfma_bias<<<gg, 256, 0, stream>>>(rlnh, rlnl, qwh, qwl, qb, qbuf);
    k_gemm_mfma_bias<<<gg, 256, 0, stream>>>(olnh, olnl, bwh, bwl, bb, bbuf);

    k_norm<<<16384, 256, 0, stream>>>(qbuf, bbuf, qinv, binv);

    // pack projections to split-bf16 (order: packq reads qbuf before packb overwrites slot3)
    k_packq<<<6144, 256, 0, stream>>>(qbuf, qh, ql);
    k_packb<<<512, 256, 0, stream>>>(bbuf, bh2, bl2, bth, btl);
    // bbuf dead: pack proj weights into slot4
    k_packw<<<576, 256, 0, stream>>>(pw, pwh, pwl, 147456);

    dim3 ga(8, 8, 64);      // n-tiles, m-tiles, z
    k_attn_mfma<<<ga, 256, 0, stream>>>(qh, ql, bh2, bl2, qinv, binv, rs, attn);

    dim3 go(1, 8, 64);      // N=96 single tile, 8 m-tiles, z
    k_out_mfma<<<go, 256, 0, stream>>>(attn, bth, btl, tokh, tokl);

    k_proj_mfma<<<gg, 256, 0, stream>>>(tokh, tokl, pwh, pwl, pb, out0);
}

// Round 3
// 796.075 us; speedup vs baseline: 1.5569x; 1.2560x over previous
//
#include <hip/hip_runtime.h>
#include <hip/hip_bf16.h>
#include <math.h>

// ---------- problem constants ----------
// x (2,3,512,512); grid 64x64 tokens of 768 ch; 8 windows of 32x32=1024 tokens
// heads=8, HD=96, F=16, rope feat dim 64, ||feat||^2 = 32 exactly.

typedef __attribute__((ext_vector_type(8))) short short8;   // 8 bf16 (4 VGPRs)
typedef __attribute__((ext_vector_type(4))) float f32x4;    // MFMA accumulator
typedef __attribute__((ext_vector_type(4))) unsigned short us4;

// bf16 split helpers: v ~= hi + lo with ~16-bit effective mantissa
__device__ __forceinline__ unsigned short f2bf(float f) {
    unsigned u = __float_as_uint(f);
    return (unsigned short)((u + 0x7FFFu + ((u >> 16) & 1u)) >> 16);   // RNE
}
__device__ __forceinline__ float bf2f(unsigned short h) { return __uint_as_float(((unsigned)h) << 16); }
__device__ __forceinline__ void split4(float4 v, us4& h4, us4& l4) {
    unsigned short h0 = f2bf(v.x), h1 = f2bf(v.y), h2 = f2bf(v.z), h3 = f2bf(v.w);
    h4 = (us4){h0, h1, h2, h3};
    l4 = (us4){f2bf(v.x - bf2f(h0)), f2bf(v.y - bf2f(h1)),
               f2bf(v.z - bf2f(h2)), f2bf(v.w - bf2f(h3))};
}

// async global->LDS, 16B per lane; LDS dest must be uniform base + lane*16
__device__ __forceinline__ void gload16(const unsigned short* g, unsigned short* l)
{
    __builtin_amdgcn_global_load_lds(
        (const __attribute__((address_space(1))) void*)(g),
        (__attribute__((address_space(3))) void*)(l), 16, 0, 0);
}

// ---------------- bilinear 2x resize (clamp-to-edge == jax renormalized) ----------------
__global__ __launch_bounds__(256) void k_resize(const float* __restrict__ x, float* __restrict__ rx)
{
    int idx = blockIdx.x * 256 + threadIdx.x;           // < 6291456 exactly
    int X = idx & 1023;
    int Y = (idx >> 10) & 1023;
    int bc = idx >> 20;                                 // 0..5 (b*3+c)
    float sy = Y * 0.5f - 0.25f;
    float sx = X * 0.5f - 0.25f;
    int y0 = (int)floorf(sy), x0 = (int)floorf(sx);
    float fy = sy - (float)y0, fx = sx - (float)x0;
    int y1 = y0 + 1, x1 = x0 + 1;
    y0 = max(0, min(511, y0)); y1 = max(0, min(511, y1));
    x0 = max(0, min(511, x0)); x1 = max(0, min(511, x1));
    const float* p = x + (size_t)bc * (512 * 512);
    float v00 = p[y0 * 512 + x0], v01 = p[y0 * 512 + x1];
    float v10 = p[y1 * 512 + x0], v11 = p[y1 * 512 + x1];
    rx[idx] = (1.f - fy) * ((1.f - fx) * v00 + fx * v01) + fy * ((1.f - fx) * v10 + fx * v11);
}

// ---------------- rope relative table R[dy+31][dx+31] ----------------
__global__ void k_rsmall(float* __restrict__ rs)
{
    int e = blockIdx.x * 256 + threadIdx.x;
    if (e >= 63 * 63) return;
    float dy = (float)(e / 63 - 31);
    float dx = (float)(e % 63 - 31);
    float s = 0.f;
    for (int f = 0; f < 16; f++) {
        float invf = powf(10.0f, -(float)f / 16.0f);
        s += cosf(dx * invf) + cosf(dy * invf);
    }
    rs[e] = s;
}

// ---------------- resize conv as tile GEMM: tokens(8192) x K(256) x ch(768, 3 groups) ----------------
__global__ __launch_bounds__(256) void k_convr(
    const float* __restrict__ rx, const float* __restrict__ wgt,
    const float* __restrict__ bias, const float* __restrict__ pe,
    float* __restrict__ out)
{
    __shared__ float As[16][68];
    __shared__ float Bs[16][68];
    int tid = threadIdx.x;
    int m0 = blockIdx.y * 64;         // token tile
    int cbase = blockIdx.x * 64;      // channel tile (stays within one group: 256%64==0)
    int ic = cbase >> 8;              // input channel for this group
    int ar = tid >> 2, ac = (tid & 3) * 4;
    int ty = tid >> 4, tx = tid & 15;

    int mtok = m0 + ar;
    int w = mtok >> 10, l = mtok & 1023;
    int b = w >> 2, wm = (w >> 1) & 1, wn = w & 1;
    int gy = wm * 32 + (l >> 5), gx = wn * 32 + (l & 31);
    const float* abase = rx + ((size_t)(b * 3 + ic) * 1024 + gy * 16) * 1024 + gx * 16;
    const float* bbase = wgt + (size_t)(cbase + ar) * 256;

    float acc[4][4] = {};
    for (int k0 = 0; k0 < 256; k0 += 16) {
        float4 av = *(const float4*)(abase + (size_t)(k0 >> 4) * 1024 + ac);
        float4 bv = *(const float4*)(bbase + k0 + ac);
        As[ac + 0][ar] = av.x; As[ac + 1][ar] = av.y; As[ac + 2][ar] = av.z; As[ac + 3][ar] = av.w;
        Bs[ac + 0][ar] = bv.x; Bs[ac + 1][ar] = bv.y; Bs[ac + 2][ar] = bv.z; Bs[ac + 3][ar] = bv.w;
        __syncthreads();
#pragma unroll
        for (int k = 0; k < 16; k++) {
            float4 a4 = *(const float4*)&As[k][ty * 4];
            float4 b4 = *(const float4*)&Bs[k][tx * 4];
            float a[4] = {a4.x, a4.y, a4.z, a4.w};
            float bb2[4] = {b4.x, b4.y, b4.z, b4.w};
#pragma unroll
            for (int r = 0; r < 4; r++)
#pragma unroll
                for (int c = 0; c < 4; c++) acc[r][c] += a[r] * bb2[c];
        }
        __syncthreads();
    }
#pragma unroll
    for (int r = 0; r < 4; r++) {
        int t = m0 + ty * 4 + r;
        int tw = t >> 10, tl = t & 1023;
        int tgy = ((tw >> 1) & 1) * 32 + (tl >> 5);
        int tgx = (tw & 1) * 32 + (tl & 31);
#pragma unroll
        for (int c = 0; c < 4; c++) {
            int cc = cbase + tx * 4 + c;
            out[(size_t)t * 768 + cc] = acc[r][c] + bias[cc] + pe[(size_t)cc * 4096 + tgy * 64 + tgx];
        }
    }
}

// ---------------- origin conv as tile GEMM: tokens(8192) x K(64) x ch(768, 3 groups) ----------------
__global__ __launch_bounds__(256) void k_convo(
    const float* __restrict__ x, const float* __restrict__ wgt,
    const float* __restrict__ bias, float* __restrict__ out)
{
    __shared__ float As[16][68];
    __shared__ float Bs[16][68];
    int tid = threadIdx.x;
    int m0 = blockIdx.y * 64;
    int cbase = blockIdx.x * 64;
    int ic = cbase >> 8;
    int ar = tid >> 2, ac = (tid & 3) * 4;
    int ty = tid >> 4, tx = tid & 15;

    int mtok = m0 + ar;
    int w = mtok >> 10, l = mtok & 1023;
    int b = w >> 2, wm = (w >> 1) & 1, wn = w & 1;
    int gy = wm * 32 + (l >> 5), gx = wn * 32 + (l & 31);
    const float* abase = x + ((size_t)(b * 3 + ic) * 512 + gy * 8) * 512 + gx * 8;
    const float* bbase = wgt + (size_t)(cbase + ar) * 64;

    float acc[4][4] = {};
    for (int k0 = 0; k0 < 64; k0 += 16) {
        int k = k0 + ac;
        float4 av = *(const float4*)(abase + (size_t)(k >> 3) * 512 + (k & 7));
        float4 bv = *(const float4*)(bbase + k);
        As[ac + 0][ar] = av.x; As[ac + 1][ar] = av.y; As[ac + 2][ar] = av.z; As[ac + 3][ar] = av.w;
        Bs[ac + 0][ar] = bv.x; Bs[ac + 1][ar] = bv.y; Bs[ac + 2][ar] = bv.z; Bs[ac + 3][ar] = bv.w;
        __syncthreads();
#pragma unroll
        for (int k2 = 0; k2 < 16; k2++) {
            float4 a4 = *(const float4*)&As[k2][ty * 4];
            float4 b4 = *(const float4*)&Bs[k2][tx * 4];
            float a[4] = {a4.x, a4.y, a4.z, a4.w};
            float bb2[4] = {b4.x, b4.y, b4.z, b4.w};
#pragma unroll
            for (int r = 0; r < 4; r++)
#pragma unroll
                for (int c = 0; c < 4; c++) acc[r][c] += a[r] * bb2[c];
        }
        __syncthreads();
    }
#pragma unroll
    for (int r = 0; r < 4; r++) {
        int t = m0 + ty * 4 + r;
#pragma unroll
        for (int c = 0; c < 4; c++) {
            int cc = cbase + tx * 4 + c;
            out[(size_t)t * 768 + cc] = acc[r][c] + bias[cc];
        }
    }
}

// ---------------- LayerNorm fused with split-bf16 pack: one block per token ----------------
__global__ __launch_bounds__(256) void k_ln_pack(
    const float* __restrict__ in, const float* __restrict__ g,
    const float* __restrict__ beta, unsigned short* __restrict__ oh,
    unsigned short* __restrict__ ol)
{
    int blk = blockIdx.x;
    int tid = threadIdx.x;
    __shared__ float redA[256], redB[256];
    float v[3];
#pragma unroll
    for (int r = 0; r < 3; r++) v[r] = in[(size_t)blk * 768 + r * 256 + tid];
    float s = v[0] + v[1] + v[2];
    float sq = v[0] * v[0] + v[1] * v[1] + v[2] * v[2];
    redA[tid] = s; redB[tid] = sq;
    __syncthreads();
    for (int off = 128; off > 0; off >>= 1) {
        if (tid < off) { redA[tid] += redA[tid + off]; redB[tid] += redB[tid + off]; }
        __syncthreads();
    }
    float mu = redA[0] * (1.0f / 768.0f);
    float var = redB[0] * (1.0f / 768.0f) - mu * mu;
    float rstd = rsqrtf(var + 1e-5f);
#pragma unroll
    for (int r = 0; r < 3; r++) {
        int c = r * 256 + tid;
        float y = (v[r] - mu) * rstd * g[c] + beta[c];
        unsigned short hv = f2bf(y);
        oh[(size_t)blk * 768 + c] = hv;
        ol[(size_t)blk * 768 + c] = f2bf(y - bf2f(hv));
    }
}

// ---------------- generic fp32 -> split-bf16 weight pack ----------------
__global__ __launch_bounds__(256) void k_packw(
    const float* __restrict__ src, unsigned short* __restrict__ dh,
    unsigned short* __restrict__ dl, int n4)
{
    int idx = blockIdx.x * 256 + threadIdx.x;
    if (idx >= n4) return;
    float4 v = ((const float4*)src)[idx];
    us4 h, l; split4(v, h, l);
    ((us4*)dh)[idx] = h;
    ((us4*)dl)[idx] = l;
}

// ---------------- per-(w,h,l) inverse norms: rsqrt(||q96||^2 + 32) ----------------
__global__ __launch_bounds__(256) void k_norm(
    const float* __restrict__ qbuf, const float* __restrict__ bbuf,
    float* __restrict__ qinv, float* __restrict__ binv)
{
    int blk = blockIdx.x;
    int tid = threadIdx.x;
    int which = blk >> 13;
    int row = blk & 8191;                  // w*1024 + l
    const float* src = (which ? bbuf : qbuf) + (size_t)row * 768;
    float* dst = which ? binv : qinv;
    __shared__ float sq[768];
#pragma unroll
    for (int r = 0; r < 3; r++) { int c = r * 256 + tid; float vv = src[c]; sq[c] = vv * vv; }
    __syncthreads();
    if (tid < 8) {
        float s = 32.0f;
        const float* p = sq + tid * 96;
#pragma unroll
        for (int d = 0; d < 96; d++) s += p[d];
        int w = row >> 10, l = row & 1023;
        dst[(size_t)(w * 8 + tid) * 1024 + l] = rsqrtf(s);
    }
}

// ---------------- pack q: fp32 [w*1024+l][768] head-slices -> hi/lo bf16 [z][1024][96] ----------------
__global__ __launch_bounds__(256) void k_packq(
    const float* __restrict__ src, unsigned short* __restrict__ dh, unsigned short* __restrict__ dl)
{
    int idx = blockIdx.x * 256 + threadIdx.x;     // 64*1024*24 = 1572864 quads
    int dq = idx % 24;
    int rest = idx / 24;
    int l = rest & 1023, z = rest >> 10;
    int w = z >> 3, h = z & 7;
    float4 v = *(const float4*)(src + (size_t)((w << 10) + l) * 768 + h * 96 + dq * 4);
    us4 hv, lv; split4(v, hv, lv);
    size_t o = ((size_t)(z << 10) + l) * 96 + dq * 4;
    *(us4*)(dh + o) = hv;
    *(us4*)(dl + o) = lv;
}

// ---------------- pack b: hi/lo [z][1024][96] + transposed hi/lo [z][96][1024] ----------------
__global__ __launch_bounds__(256) void k_packb(
    const float* __restrict__ src, unsigned short* __restrict__ dh, unsigned short* __restrict__ dl,
    unsigned short* __restrict__ th, unsigned short* __restrict__ tl)
{
    __shared__ float T[128][97];
    int z = blockIdx.x >> 3, lt = blockIdx.x & 7;     // 64 z * 8 row-tiles of 128
    int w = z >> 3, h = z & 7;
    int tid = threadIdx.x;
#pragma unroll
    for (int rq = 0; rq < 12; rq++) {                 // 128*24 quads / 256 threads
        int q = rq * 256 + tid;
        int l = q / 24, dq = (q % 24) * 4;
        float4 v = *(const float4*)(src + (size_t)((w << 10) + lt * 128 + l) * 768 + h * 96 + dq);
        us4 hv, lv; split4(v, hv, lv);
        size_t o = ((size_t)(z << 10) + lt * 128 + l) * 96 + dq;
        *(us4*)(dh + o) = hv;
        *(us4*)(dl + o) = lv;
        T[l][dq + 0] = v.x; T[l][dq + 1] = v.y; T[l][dq + 2] = v.z; T[l][dq + 3] = v.w;
    }
    __syncthreads();
#pragma unroll
    for (int rq = 0; rq < 12; rq++) {                 // 96*32 quads / 256 threads
        int q = rq * 256 + tid;
        int d = q >> 5, lq = (q & 31) * 4;
        float4 v = make_float4(T[lq + 0][d], T[lq + 1][d], T[lq + 2][d], T[lq + 3][d]);
        us4 hv, lv; split4(v, hv, lv);
        size_t o = ((size_t)z * 96 + d) * 1024 + lt * 128 + lq;
        *(us4*)(th + o) = hv;
        *(us4*)(tl + o) = lv;
    }
}

// ---------------- shared MFMA helpers ----------------
__device__ __forceinline__ void mfma_block44(
    short8 afh[4], short8 afl[4], short8 bfh[4], short8 bfl[4], f32x4 acc[4][4])
{
#pragma unroll
    for (int mi = 0; mi < 4; mi++)
#pragma unroll
        for (int ni = 0; ni < 4; ni++) {
            f32x4 c = acc[mi][ni];
            c = __builtin_amdgcn_mfma_f32_16x16x32_bf16(afh[mi], bfh[ni], c, 0, 0, 0);
            c = __builtin_amdgcn_mfma_f32_16x16x32_bf16(afh[mi], bfl[ni], c, 0, 0, 0);
            c = __builtin_amdgcn_mfma_f32_16x16x32_bf16(afl[mi], bfh[ni], c, 0, 0, 0);
            acc[mi][ni] = c;
        }
}

// ======== LDS-staged 128x128 GEMM core (m97 structure), hi/lo split-bf16 ========
// operands: A[row][K] hi/lo, B[row][K] hi/lo, K % 32 == 0, K contiguous (ld == K)
// LDS per stage: 4 tiles of [128][32] bf16, chunk-swizzled: chunk' = chunk ^ ((row>>1)&3)

// stage one [128][32] bf16 tile; 256 threads, 2 chunks each (16B chunks)
__device__ __forceinline__ void stage_tile(
    const unsigned short* __restrict__ src, unsigned short* lbuf,
    int mbase, int K, int kofs, int tid)
{
    int row = tid >> 2;
    int kc  = tid & 3;
    int v   = (row >> 1) & 3;        // invariant under row += 64
    int kcs = (kc ^ v) << 3;
#pragma unroll
    for (int j = 0; j < 2; j++) {
        int r = row + j * 64;
        const unsigned short* g = src + (size_t)(mbase + r) * K + kofs + kcs;
        gload16(g, lbuf + r * 32 + (kc << 3));     // LDS linear: uniform base + lane*16
    }
}

__device__ __forceinline__ void stage4(
    const unsigned short* __restrict__ Ah, const unsigned short* __restrict__ Al,
    const unsigned short* __restrict__ Bh, const unsigned short* __restrict__ Bl,
    unsigned short* lds_stage, int m0, int n0, int K, int kofs, int tid)
{
    stage_tile(Ah, lds_stage,         m0, K, kofs, tid);
    stage_tile(Al, lds_stage + 4096,  m0, K, kofs, tid);
    stage_tile(Bh, lds_stage + 8192,  n0, K, kofs, tid);
    stage_tile(Bl, lds_stage + 12288, n0, K, kofs, tid);
}

__device__ __forceinline__ void frags_from_lds(
    const unsigned short* lds_stage, int wm, int wn, int lrow, int lgrp,
    short8 afh[4], short8 afl[4], short8 bfh[4], short8 bfl[4])
{
    int ch = (lgrp ^ ((lrow >> 1) & 3)) * 8;      // swizzled chunk (row bits >16 don't affect)
    const unsigned short* Ah = lds_stage;
    const unsigned short* Al = lds_stage + 4096;
    const unsigned short* Bh = lds_stage + 8192;
    const unsigned short* Bl = lds_stage + 12288;
#pragma unroll
    for (int mi = 0; mi < 4; mi++) {
        int row = wm * 64 + mi * 16 + lrow;
        afh[mi] = *(const short8*)(Ah + row * 32 + ch);
        afl[mi] = *(const short8*)(Al + row * 32 + ch);
    }
#pragma unroll
    for (int ni = 0; ni < 4; ni++) {
        int row = wn * 64 + ni * 16 + lrow;
        bfh[ni] = *(const short8*)(Bh + row * 32 + ch);
        bfl[ni] = *(const short8*)(Bl + row * 32 + ch);
    }
}

__device__ __forceinline__ void gemm_lds_core(
    const unsigned short* __restrict__ Ah, const unsigned short* __restrict__ Al,
    const unsigned short* __restrict__ Bh, const unsigned short* __restrict__ Bl,
    unsigned short* lds, int m0, int n0, int K, f32x4 acc[4][4])
{
    int tid = threadIdx.x, lane = tid & 63, wid = tid >> 6;
    int wm = wid >> 1, wn = wid & 1, lrow = lane & 15, lgrp = lane >> 4;
    int nkt = K >> 5;
    stage4(Ah, Al, Bh, Bl, lds, m0, n0, K, 0, tid);
    __syncthreads();
    for (int kt = 0; kt < nkt; kt++) {
        int cur = kt & 1;
        if (kt + 1 < nkt)
            stage4(Ah, Al, Bh, Bl, lds + (cur ^ 1) * 16384, m0, n0, K, (kt + 1) << 5, tid);
        short8 afh[4], afl[4], bfh[4], bfl[4];
        frags_from_lds(lds + cur * 16384, wm, wn, lrow, lgrp, afh, afl, bfh, bfl);
        mfma_block44(afh, afl, bfh, bfl, acc);
        __syncthreads();
    }
}

// ---------------- MFMA GEMM: C[M=8192][768] = A * B^T + bias ----------------
__global__ __launch_bounds__(256) void k_gemm_mfma_bias(
    const unsigned short* __restrict__ Ah, const unsigned short* __restrict__ Al,
    const unsigned short* __restrict__ Bh, const unsigned short* __restrict__ Bl,
    const float* __restrict__ bias, float* __restrict__ C)
{
    __shared__ unsigned short lds[2][16384];
    int tid = threadIdx.x, lane = tid & 63, wid = tid >> 6;
    int wm = wid >> 1, wn = wid & 1;
    int lrow = lane & 15, lgrp = lane >> 4;
    int m0 = blockIdx.y * 128, n0 = blockIdx.x * 128;
    f32x4 acc[4][4] = {};
    gemm_lds_core(Ah, Al, Bh, Bl, &lds[0][0], m0, n0, 768, acc);

    int ibase = m0 + wm * 64 + lgrp * 4;
    int jbase = n0 + wn * 64 + lrow;
#pragma unroll
    for (int ni = 0; ni < 4; ni++) {
        int j = jbase + ni * 16;
        float bj = bias[j];
#pragma unroll
        for (int mi = 0; mi < 4; mi++) {
            int ib = ibase + mi * 16;
#pragma unroll
            for (int r = 0; r < 4; r++)
                C[(size_t)(ib + r) * 768 + j] = acc[mi][ni][r] + bj;
        }
    }
}

// ---------------- MFMA proj: out0[b][cc][p] = tok * projw^T + projb ----------------
__global__ __launch_bounds__(256) void k_proj_mfma(
    const unsigned short* __restrict__ Ah, const unsigned short* __restrict__ Al,
    const unsigned short* __restrict__ Bh, const unsigned short* __restrict__ Bl,
    const float* __restrict__ pb, float* __restrict__ out0)
{
    __shared__ unsigned short lds[2][16384];
    int tid = threadIdx.x, lane = tid & 63, wid = tid >> 6;
    int wm = wid >> 1, wn = wid & 1;
    int lrow = lane & 15, lgrp = lane >> 4;
    int m0 = blockIdx.y * 128, n0 = blockIdx.x * 128;
    f32x4 acc[4][4] = {};
    gemm_lds_core(Ah, Al, Bh, Bl, &lds[0][0], m0, n0, 768, acc);

    int ibase = m0 + wm * 64 + lgrp * 4;
    int jbase = n0 + wn * 64 + lrow;
#pragma unroll
    for (int ni = 0; ni < 4; ni++) {
        int cc = jbase + ni * 16;
        float bj = pb[cc];
        float* obase = out0 + (size_t)cc * 4096;
#pragma unroll
        for (int mi = 0; mi < 4; mi++) {
            int i0 = ibase + mi * 16;           // 4 consecutive token rows i0..i0+3
            float4 v = make_float4(acc[mi][ni][0] + bj, acc[mi][ni][1] + bj,
                                   acc[mi][ni][2] + bj, acc[mi][ni][3] + bj);
            *(float4*)(obase + (size_t)(i0 >> 12) * 3145728 + (i0 & 4095)) = v;
        }
    }
}

// ================= MFMA attn: per (z) S = (Q*B^T + R) scaled; LDS-staged =================
__global__ __launch_bounds__(256) void k_attn_mfma(
    const unsigned short* __restrict__ qh_, const unsigned short* __restrict__ ql_,
    const unsigned short* __restrict__ bh_, const unsigned short* __restrict__ bl_,
    const float* __restrict__ qinv, const float* __restrict__ binv,
    const float* __restrict__ rs, float* __restrict__ attn)
{
    __shared__ unsigned short lds[2][16384];
    int z = blockIdx.z;
    int n0 = blockIdx.x * 128, m0 = blockIdx.y * 128;
    int tid = threadIdx.x;
    int lane = tid & 63, wid = tid >> 6;
    int wm = wid >> 1, wn = wid & 1;
    int lrow = lane & 15, lgrp = lane >> 4;

    size_t zoff = (size_t)z * 1024 * 96;
    f32x4 acc[4][4] = {};
    gemm_lds_core(qh_ + zoff, ql_ + zoff, bh_ + zoff, bl_ + zoff,
                  &lds[0][0], m0, n0, 96, acc);

    // epilogue: C[i][j] = (dot + R[dy][dx]) * qinv[i] * binv[j]
    float* Cz = attn + ((size_t)z << 20);
    const float* qiz = qinv + (z << 10);
    const float* biz = binv + (z << 10);
    int ibase = m0 + wm * 64 + lgrp * 4;
    int jbase = n0 + wn * 64 + lrow;

    float qv[16];
#pragma unroll
    for (int mi = 0; mi < 4; mi++)
#pragma unroll
        for (int r = 0; r < 4; r++) qv[mi * 4 + r] = qiz[ibase + mi * 16 + r];

#pragma unroll
    for (int ni = 0; ni < 4; ni++) {
        int j = jbase + ni * 16;
        float bj = biz[j];
        int jy = j >> 5, jx = j & 31;
#pragma unroll
        for (int mi = 0; mi < 4; mi++) {
#pragma unroll
            for (int r = 0; r < 4; r++) {
                int i = ibase + mi * 16 + r;
                int dy = (i >> 5) - jy + 31;
                int dx = (i & 31) - jx + 31;
                Cz[(size_t)i * 1024 + j] = (acc[mi][ni][r] + rs[dy * 63 + dx]) * qv[mi * 4 + r] * bj;
            }
        }
    }
}

// ================= MFMA out: per z O = S * B; M=1024 N=96 K=1024; split-bf16 =================
__device__ __forceinline__ void stage_cvt_write(
    unsigned short (*Ah)[40], unsigned short (*Al)[40], int srow, int skb,
    float4 a, float4 b, float4 c, float4 d)
{
    us4 h0, l0, h1, l1, h2, l2, h3, l3;
    split4(a, h0, l0); split4(b, h1, l1); split4(c, h2, l2); split4(d, h3, l3);
    *(us4*)&Ah[srow][skb + 0]  = h0; *(us4*)&Al[srow][skb + 0]  = l0;
    *(us4*)&Ah[srow][skb + 4]  = h1; *(us4*)&Al[srow][skb + 4]  = l1;
    *(us4*)&Ah[srow][skb + 8]  = h2; *(us4*)&Al[srow][skb + 8]  = l2;
    *(us4*)&Ah[srow][skb + 12] = h3; *(us4*)&Al[srow][skb + 12] = l3;
}

__global__ __launch_bounds__(256) void k_out_mfma(
    const float* __restrict__ attn, const unsigned short* __restrict__ bth,
    const unsigned short* __restrict__ btl, unsigned short* __restrict__ tokh,
    unsigned short* __restrict__ tokl)
{
    __shared__ unsigned short AhS[2][128][40];
    __shared__ unsigned short AlS[2][128][40];
    int z = blockIdx.z, m0 = blockIdx.y * 128;
    int w = z >> 3, h = z & 7;
    int tid = threadIdx.x, lane = tid & 63, wid = tid >> 6;
    int lrow = lane & 15, lgrp = lane >> 4;

    const float* A = attn + ((size_t)z << 20) + (size_t)m0 * 1024;
    const unsigned short* Bh = bth + (size_t)z * 98304;   // [96][1024]
    const unsigned short* Bl = btl + (size_t)z * 98304;

    int srow = tid >> 1, skb = (tid & 1) * 16;
    const float* sp = A + (size_t)srow * 1024 + skb;

    f32x4 acc[2][6] = {};

    // prologue: stage k-tile 0
    float4 sv0 = *(const float4*)(sp + 0);
    float4 sv1 = *(const float4*)(sp + 4);
    float4 sv2 = *(const float4*)(sp + 8);
    float4 sv3 = *(const float4*)(sp + 12);
    stage_cvt_write(AhS[0], AlS[0], srow, skb, sv0, sv1, sv2, sv3);
    __syncthreads();

    for (int kt = 0; kt < 32; kt++) {
        int cur = kt & 1;
        if (kt < 31) {                       // issue next-tile global loads early
            const float* p = sp + (kt + 1) * 32;
            sv0 = *(const float4*)(p + 0);
            sv1 = *(const float4*)(p + 4);
            sv2 = *(const float4*)(p + 8);
            sv3 = *(const float4*)(p + 12);
        }
        short8 bfh[6], bfl[6];
#pragma unroll
        for (int ni = 0; ni < 6; ni++) {
            size_t o = (size_t)(ni * 16 + lrow) * 1024 + kt * 32 + lgrp * 8;
            bfh[ni] = *(const short8*)(Bh + o);
            bfl[ni] = *(const short8*)(Bl + o);
        }
        short8 afh[2], afl[2];
#pragma unroll
        for (int mi = 0; mi < 2; mi++) {
            int r = wid * 32 + mi * 16 + lrow;
            afh[mi] = *(const short8*)&AhS[cur][r][lgrp * 8];
            afl[mi] = *(const short8*)&AlS[cur][r][lgrp * 8];
        }
#pragma unroll
        for (int mi = 0; mi < 2; mi++)
#pragma unroll
            for (int ni = 0; ni < 6; ni++) {
                f32x4 c = acc[mi][ni];
                c = __builtin_amdgcn_mfma_f32_16x16x32_bf16(afh[mi], bfh[ni], c, 0, 0, 0);
                c = __builtin_amdgcn_mfma_f32_16x16x32_bf16(afh[mi], bfl[ni], c, 0, 0, 0);
                c = __builtin_amdgcn_mfma_f32_16x16x32_bf16(afl[mi], bfh[ni], c, 0, 0, 0);
                acc[mi][ni] = c;
            }
        if (kt < 31) stage_cvt_write(AhS[cur ^ 1], AlS[cur ^ 1], srow, skb, sv0, sv1, sv2, sv3);
        __syncthreads();
    }

    // epilogue: scatter split-bf16 to token layout (consumed by proj MFMA)
    int b = w >> 2, wm = (w >> 1) & 1, wn = w & 1;
#pragma unroll
    for (int mi = 0; mi < 2; mi++) {
#pragma unroll
        for (int r = 0; r < 4; r++) {
            int i = m0 + wid * 32 + mi * 16 + lgrp * 4 + r;
            int t = (b * 64 + wm * 32 + (i >> 5)) * 64 + wn * 32 + (i & 31);
            size_t base = (size_t)t * 768 + h * 96;
#pragma unroll
            for (int ni = 0; ni < 6; ni++) {
                float v = acc[mi][ni][r];
                unsigned short hv = f2bf(v);
                tokh[base + ni * 16 + lrow] = hv;
                tokl[base + ni * 16 + lrow] = f2bf(v - bf2f(hv));
            }
        }
    }
}

extern "C" void kernel_launch(void* const* d_in, const int* in_sizes, int n_in,
                              void* d_out, int out_size, void* d_ws, size_t ws_size,
                              hipStream_t stream)
{
    const float* x   = (const float*)d_in[0];
    const float* ow  = (const float*)d_in[1];
    const float* ob  = (const float*)d_in[2];
    const float* rw  = (const float*)d_in[3];
    const float* rb  = (const float*)d_in[4];
    const float* pe  = (const float*)d_in[5];
    const float* nbg = (const float*)d_in[6];
    const float* nbb = (const float*)d_in[7];
    const float* nqg = (const float*)d_in[8];
    const float* nqb = (const float*)d_in[9];
    const float* qw  = (const float*)d_in[10];
    const float* qb  = (const float*)d_in[11];
    const float* bw  = (const float*)d_in[12];
    const float* bb  = (const float*)d_in[13];
    const float* pw  = (const float*)d_in[14];
    const float* pb  = (const float*)d_in[15];

    float* out0 = (float*)d_out;                 // (2,768,64,64) = 6291456
    float* attn = out0 + 6291456;                // (8,8,1024,1024) = 67108864

    float* ws   = (float*)d_ws;
    float* rx   = ws;                            // slot0
    float* slot1 = ws + 1 * 6291456;
    float* slot2 = ws + 2 * 6291456;
    float* slot3 = ws + 3 * 6291456;
    float* slot4 = ws + 4 * 6291456;
    float* qinv = ws + 5 * 6291456;              // 65536
    float* binv = qinv + 65536;                  // 65536
    float* rs   = binv + 65536;                  // 3969

    float* rpre = slot3;                         // pre-LN resize conv out
    float* opre = slot4;                         // pre-LN origin conv out
    float* qbuf = slot3;                         // q projection fp32 (overwrites rpre)
    float* bbuf = slot4;                         // b projection fp32 (overwrites opre)

    // LN'd activations, split-bf16 (each slot = 25165824 B = 2 x 12582912 B)
    unsigned short* rlnh = (unsigned short*)slot2;
    unsigned short* rlnl = rlnh + 6291456;
    unsigned short* olnh = (unsigned short*)slot1;
    unsigned short* olnl = olnh + 6291456;

    // packed weights: qw/bw in slot0 (rx dead after convr; dead before k_out writes tok)
    unsigned short* qwh = (unsigned short*)rx;
    unsigned short* qwl = qwh + 589824;
    unsigned short* bwh = qwh + 2 * 589824;
    unsigned short* bwl = qwh + 3 * 589824;
    // projw packed in slot4 (bbuf dead after packb)
    unsigned short* pwh = (unsigned short*)slot4;
    unsigned short* pwl = pwh + 589824;

    // per-head packed q/b (overwrite dead LN buffers)
    unsigned short* qh  = (unsigned short*)slot2;   // after q GEMM, rln dead
    unsigned short* ql  = qh + 6291456;
    unsigned short* bh2 = (unsigned short*)slot1;   // after b GEMM, oln dead
    unsigned short* bl2 = bh2 + 6291456;
    unsigned short* bth = (unsigned short*)slot3;   // after norm+packq, qbuf dead
    unsigned short* btl = bth + 6291456;

    // tok split-bf16 in slot0 (qw/bw packs dead after b GEMM)
    unsigned short* tokh = (unsigned short*)rx;
    unsigned short* tokl = tokh + 6291456;

    k_resize<<<24576, 256, 0, stream>>>(x, rx);
    k_rsmall<<<16, 256, 0, stream>>>(rs);

    dim3 gc(12, 128);
    k_convr<<<gc, 256, 0, stream>>>(rx, rw, rb, pe, rpre);
    // rx dead now: pack q/b weights into slot0
    k_packw<<<576, 256, 0, stream>>>(qw, qwh, qwl, 147456);
    k_packw<<<576, 256, 0, stream>>>(bw, bwh, bwl, 147456);
    k_convo<<<gc, 256, 0, stream>>>(x, ow, ob, opre);

    k_ln_pack<<<8192, 256, 0, stream>>>(rpre, nqg, nqb, rlnh, rlnl);
    k_ln_pack<<<8192, 256, 0, stream>>>(opre, nbg, nbb, olnh, olnl);

    dim3 gg(6, 64);     // N=768/128, M=8192/128
    k_gemm_mfma_bias<<<gg, 256, 0, stream>>>(rlnh, rlnl, qwh, qwl, qb, qbuf);
    k_gemm_mfma_bias<<<gg, 256, 0, stream>>>(olnh, olnl, bwh, bwl, bb, bbuf);

    k_norm<<<16384, 256, 0, stream>>>(qbuf, bbuf, qinv, binv);

    // pack projections to split-bf16 (order: packq reads qbuf before packb overwrites slot3)
    k_packq<<<6144, 256, 0, stream>>>(qbuf, qh, ql);
    k_packb<<<512, 256, 0, stream>>>(bbuf, bh2, bl2, bth, btl);
    // bbuf dead: pack proj weights into slot4
    k_packw<<<576, 256, 0, stream>>>(pw, pwh, pwl, 147456);

    dim3 ga(8, 8, 64);      // n-tiles, m-tiles, z
    k_attn_mfma<<<ga, 256, 0, stream>>>(qh, ql, bh2, bl2, qinv, binv, rs, attn);

    dim3 go(1, 8, 64);      // N=96 single tile, 8 m-tiles, z
    k_out_mfma<<<go, 256, 0, stream>>>(attn, bth, btl, tokh, tokl);

    k_proj_mfma<<<gg, 256, 0, stream>>>(tokh, tokl, pwh, pwl, pb, out0);
}